// Round 2
// baseline (212.966 us; speedup 1.0000x reference)
//
#include <hip/hip_runtime.h>

// ---------------- types / helpers ----------------
typedef __attribute__((ext_vector_type(8))) __bf16 bf16x8;
typedef __attribute__((ext_vector_type(4))) __bf16 bf16x4;
typedef __attribute__((ext_vector_type(4))) float  f32x4;

__device__ __forceinline__ void gld_lds16(const void* g, void* l) {
  __builtin_amdgcn_global_load_lds(
      (const __attribute__((address_space(1))) unsigned int*)g,
      (__attribute__((address_space(3))) unsigned int*)l, 16, 0, 0);
}

// Problem constants: B=2 S=2048 D=768 NQK=12 DQK=64 NOV=768 DOV=1 R=64 VKV=4
// SKV = 2052 (real+virtual keys), SKP = 2112 (padded to 33*64)

// ---------------- prep: bf16 conversions + weight transposes ----------------
// Rb  [4096][768]   = resid
// Wt1 [2304][768]   = [Wq|Wk|Wv]^T   (col n of fused QKV gemm, rows = k)
// Wt2 [768][768]    = Wo^T
__global__ __launch_bounds__(256) void prep_kernel(
    const float* __restrict__ resid, const float* __restrict__ WQ,
    const float* __restrict__ WK, const float* __restrict__ WV,
    const float* __restrict__ WO,
    __bf16* __restrict__ Rb, __bf16* __restrict__ Wt1, __bf16* __restrict__ Wt2)
{
  int t = blockIdx.x * 256 + threadIdx.x;
  if (t < 3145728) { Rb[t] = (__bf16)resid[t]; return; }
  t -= 3145728;
  if (t < 1769472) {
    int nn = t / 768, k = t - nn * 768;
    float v;
    if (nn < 768)       v = WQ[(nn >> 6) * 49152 + k * 64 + (nn & 63)];
    else if (nn < 1536) v = WK[((nn - 768) >> 6) * 49152 + k * 64 + ((nn - 768) & 63)];
    else                v = WV[(nn - 1536) * 768 + k];
    Wt1[t] = (__bf16)v;
    return;
  }
  t -= 1769472;
  int nn = t / 768, k = t - nn * 768;
  Wt2[t] = (__bf16)WO[k * 768 + nn];
}

// ---------------- bf16 GEMM: C[M][N] = A[M][K] * Bt[N][K]^T ----------------
// 128x128 tile, BK=64, 4 waves (each 64x64 quadrant, 4x4 16x16 frags),
// global_load_lds(16B) staging, XOR-swizzled LDS ((row&7)<<4).
template<int OUTF>  // 0: bf16 out, 1: f32 out
__global__ __launch_bounds__(256) void gemm_bt(
    const __bf16* __restrict__ A, const __bf16* __restrict__ Bt,
    void* __restrict__ C, int M, int N, int K, int ldc)
{
  __shared__ __align__(16) char smem[32768];
  char* a_lds = smem;
  char* b_lds = smem + 16384;
  const int tid = threadIdx.x;
  const int l = tid & 63, wv = tid >> 6;
  const int wr = wv >> 1, wc = wv & 1;
  const int l15 = l & 15, lg = l >> 4;
  const int m0 = blockIdx.y * 128, n0 = blockIdx.x * 128;
  const int sw = (l15 & 7) << 4;   // frag rows are i*16+l15 -> row&7 == l15&7

  f32x4 acc[4][4] = {};

  for (int k0 = 0; k0 < K; k0 += 64) {
    __syncthreads();
#pragma unroll
    for (int c = 0; c < 4; ++c) {   // A tile [128 m][64 k] bf16, linear LDS, pre-swizzled src
      int idx = c * 256 + tid;
      int row = idx >> 3, slt = idx & 7;
      gld_lds16(A + (m0 + row) * K + k0 + ((slt ^ (row & 7)) * 8), a_lds + idx * 16);
    }
#pragma unroll
    for (int c = 0; c < 4; ++c) {   // B tile [128 n][64 k]
      int idx = c * 256 + tid;
      int row = idx >> 3, slt = idx & 7;
      gld_lds16(Bt + (n0 + row) * K + k0 + ((slt ^ (row & 7)) * 8), b_lds + idx * 16);
    }
    __syncthreads();
#pragma unroll
    for (int kk = 0; kk < 2; ++kk) {
      bf16x8 af[4], bfr[4];
#pragma unroll
      for (int i = 0; i < 4; ++i) {
        int mr = wr * 64 + i * 16 + l15;
        af[i]  = *(const bf16x8*)(a_lds + mr * 128 + ((lg * 16 + kk * 64) ^ sw));
        int nr = wc * 64 + i * 16 + l15;
        bfr[i] = *(const bf16x8*)(b_lds + nr * 128 + ((lg * 16 + kk * 64) ^ sw));
      }
#pragma unroll
      for (int i = 0; i < 4; ++i)
#pragma unroll
        for (int j = 0; j < 4; ++j)
          acc[i][j] = __builtin_amdgcn_mfma_f32_16x16x32_bf16(af[i], bfr[j], acc[i][j], 0, 0, 0);
    }
  }
  // epilogue: D row=(lg*4+r), col=l15 per 16x16 frag
#pragma unroll
  for (int i = 0; i < 4; ++i)
#pragma unroll
    for (int j = 0; j < 4; ++j)
#pragma unroll
      for (int r = 0; r < 4; ++r) {
        int row = m0 + wr * 64 + i * 16 + lg * 4 + r;
        int col = n0 + wc * 64 + j * 16 + l15;
        if (OUTF) ((float*)C)[row * ldc + col] = acc[i][j][r];
        else      ((__bf16*)C)[row * ldc + col] = (__bf16)acc[i][j][r];
      }
}

// ---------------- rotary + Q/K layout ----------------
// Qb [24][2048][64] = rope(q + bQ)/8 ; Kb [24][2112][64] = rope(k + bK) | virtual_k | 0
__global__ __launch_bounds__(256) void qk_rotary(
    const __bf16* __restrict__ qkv, const float* __restrict__ bQ,
    const float* __restrict__ bK, const float* __restrict__ vk,
    const float* __restrict__ rsin, const float* __restrict__ rcos,
    __bf16* __restrict__ Qb, __bf16* __restrict__ Kb)
{
  int t = blockIdx.x * 256 + threadIdx.x;
  int d = t & 63;
  int x = t >> 6;
  int bh = x / 2112;
  int s = x - bh * 2112;
  int b = bh / 12, h = bh - b * 12;
  int kidx = (bh * 2112 + s) * 64 + d;
  if (s < 2048) {
    const __bf16* rowp = qkv + (b * 2048 + s) * 2304;
    int c0 = h * 64 + d, c1 = h * 64 + (d ^ 32);
    float sn = rsin[s * 64 + d], cs = rcos[s * 64 + d];
    float q1 = (float)rowp[c0] + bQ[c0];
    float q2 = (float)rowp[c1] + bQ[c1];
    float k1 = (float)rowp[768 + c0] + bK[c0];
    float k2 = (float)rowp[768 + c1] + bK[c1];
    float qr = (d < 32) ? -q2 : q2;   // rot = [-x[32:], x[:32]]
    float kr = (d < 32) ? -k2 : k2;
    Qb[(bh * 2048 + s) * 64 + d] = (__bf16)((q1 * cs + qr * sn) * 0.125f);
    Kb[kidx] = (__bf16)(k1 * cs + kr * sn);
  } else if (s < 2052) {
    Kb[kidx] = (__bf16)vk[((s - 2048) * 12 + h) * 64 + d];  // no rope, no bias
  } else {
    Kb[kidx] = (__bf16)0.0f;
  }
}

// ---------------- V transpose: Vt [24][64 dv][2112 s] ----------------
__global__ __launch_bounds__(256) void v_trans(
    const __bf16* __restrict__ qkv, const float* __restrict__ bV,
    const float* __restrict__ vv, __bf16* __restrict__ Vt)
{
  __shared__ float tile[64][65];
  int st = blockIdx.x, bh = blockIdx.y;
  int b = bh / 12, h = bh - b * 12;
  int tid = threadIdx.x;
#pragma unroll
  for (int r = 0; r < 16; ++r) {
    int li = r * 256 + tid;
    int srow = li >> 6, dcol = li & 63;
    int s = st * 64 + srow;
    float val;
    if (s < 2048)      val = (float)qkv[(b * 2048 + s) * 2304 + 1536 + h * 64 + dcol] + bV[h * 64 + dcol];
    else if (s < 2052) val = vv[(s - 2048) * 768 + h * 64 + dcol];
    else               val = 0.0f;
    tile[srow][dcol] = val;
  }
  __syncthreads();
#pragma unroll
  for (int r = 0; r < 16; ++r) {
    int li = r * 256 + tid;
    int drow = li >> 6, scol = li & 63;
    Vt[(bh * 64 + drow) * 2112 + st * 64 + scol] = (__bf16)tile[scol][drow];
  }
}

// ---------------- flash attention ----------------
// grid (32 qtiles, 24 bh). 4 waves x 16 queries. Keys in 64-tiles (<= qt+2 tiles).
// S^T = mfma(K, Q): lane owns query col l15; k = kb*16 + lg*4 + r.
// P -> bf16 via wave-private LDS slice; PV = mfma(P, V) from V^T LDS.
__global__ __launch_bounds__(256) void attn_kernel(
    const __bf16* __restrict__ Qb, const __bf16* __restrict__ Kb,
    const __bf16* __restrict__ Vt, __bf16* __restrict__ Z)
{
  __shared__ __align__(16) char smem[24576];
  char* k_lds = smem;            // [64 k][64 d] bf16, swizzled
  char* v_lds = smem + 8192;     // [64 dv][64 k] bf16, swizzled
  char* p_lds = smem + 16384;    // [64 q][64 k] bf16, swizzled (wave-private rows)
  const int tid = threadIdx.x;
  const int l = tid & 63, w = tid >> 6;
  const int l15 = l & 15, lg = l >> 4;
  const int qt = blockIdx.x, bh = blockIdx.y;
  const int b = bh / 12, n = bh - b * 12;
  const int q16 = qt * 64 + w * 16;
  const int sw = (l15 & 7) << 4;
  const int qrow = w * 16 + l15;

  const __bf16* qp = Qb + (bh * 2048 + q16 + l15) * 64 + lg * 8;
  const bf16x8 qa0 = *(const bf16x8*)qp;          // Q[q][0..31] B-frag
  const bf16x8 qa1 = *(const bf16x8*)(qp + 32);   // Q[q][32..63]

  f32x4 o[4] = {};
  float mrun = -1e30f, lrun = 0.0f;

  const __bf16* Kbase = Kb + bh * 2112 * 64;
  const __bf16* Vbase = Vt + bh * 64 * 2112;
  const int ntiles = qt + 2;

  for (int kt = 0; kt < ntiles; ++kt) {
    const int kt0 = kt * 64;
    __syncthreads();
#pragma unroll
    for (int c = 0; c < 2; ++c) {
      int idx = c * 256 + tid;
      int row = idx >> 3, slt = idx & 7;
      gld_lds16(Kbase + (kt0 + row) * 64 + ((slt ^ (row & 7)) * 8), k_lds + idx * 16);
    }
#pragma unroll
    for (int c = 0; c < 2; ++c) {
      int idx = c * 256 + tid;
      int row = idx >> 3, slt = idx & 7;
      gld_lds16(Vbase + row * 2112 + kt0 + ((slt ^ (row & 7)) * 8), v_lds + idx * 16);
    }
    __syncthreads();

    f32x4 sfr[4];
#pragma unroll
    for (int kb = 0; kb < 4; ++kb) {
      int krow = kb * 16 + l15;
      f32x4 a = {};
      bf16x8 ka0 = *(const bf16x8*)(k_lds + krow * 128 + ((lg * 16) ^ sw));
      bf16x8 ka1 = *(const bf16x8*)(k_lds + krow * 128 + ((lg * 16 + 64) ^ sw));
      a = __builtin_amdgcn_mfma_f32_16x16x32_bf16(ka0, qa0, a, 0, 0, 0);
      a = __builtin_amdgcn_mfma_f32_16x16x32_bf16(ka1, qa1, a, 0, 0, 0);
      sfr[kb] = a;
    }
    if (kt >= qt) {  // masked tiles: key visible iff k <= q+4 && k < 2052
      int qlim = q16 + l15 + 4;
#pragma unroll
      for (int kb = 0; kb < 4; ++kb)
#pragma unroll
        for (int r = 0; r < 4; ++r) {
          int kg = kt0 + kb * 16 + lg * 4 + r;
          if (kg > qlim || kg >= 2052) sfr[kb][r] = -1e30f;
        }
    }
    float tmax = -1e30f;
#pragma unroll
    for (int kb = 0; kb < 4; ++kb)
#pragma unroll
      for (int r = 0; r < 4; ++r) tmax = fmaxf(tmax, sfr[kb][r]);
    tmax = fmaxf(tmax, __shfl_xor(tmax, 16));
    tmax = fmaxf(tmax, __shfl_xor(tmax, 32));
    float mnew = fmaxf(mrun, tmax);
    float fsc = __expf(mrun - mnew);
    float rsum = 0.0f;
#pragma unroll
    for (int kb = 0; kb < 4; ++kb) {
      bf16x4 pv;
#pragma unroll
      for (int r = 0; r < 4; ++r) {
        float p = __expf(sfr[kb][r] - mnew);
        rsum += p;
        pv[r] = (__bf16)p;
      }
      *(bf16x4*)(p_lds + qrow * 128 + ((kb * 32 + lg * 8) ^ sw)) = pv;
    }
    rsum += __shfl_xor(rsum, 16);
    rsum += __shfl_xor(rsum, 32);
    lrun = lrun * fsc + rsum;
    mrun = mnew;
    f32x4 fv;
#pragma unroll
    for (int r = 0; r < 4; ++r) fv[r] = __shfl(fsc, lg * 4 + r);  // O rows are lg*4+r
#pragma unroll
    for (int dv = 0; dv < 4; ++dv) o[dv] *= fv;
#pragma unroll
    for (int kblk = 0; kblk < 2; ++kblk) {
      bf16x8 pa = *(const bf16x8*)(p_lds + qrow * 128 + ((kblk * 64 + lg * 16) ^ sw));
#pragma unroll
      for (int dv = 0; dv < 4; ++dv) {
        int vrow = dv * 16 + l15;
        bf16x8 vb = *(const bf16x8*)(v_lds + vrow * 128 + ((kblk * 64 + lg * 16) ^ sw));
        o[dv] = __builtin_amdgcn_mfma_f32_16x16x32_bf16(pa, vb, o[dv], 0, 0, 0);
      }
    }
  }
  float linv = 1.0f / lrun;
  f32x4 lv;
#pragma unroll
  for (int r = 0; r < 4; ++r) lv[r] = __shfl(linv, lg * 4 + r);
  __bf16* zbase = Z + (b * 2048 + q16) * 768 + n * 64;
#pragma unroll
  for (int dv = 0; dv < 4; ++dv)
#pragma unroll
    for (int r = 0; r < 4; ++r)
      zbase[(lg * 4 + r) * 768 + dv * 16 + l15] = (__bf16)(o[dv][r] * lv[r]);
}

// ---------------- launch ----------------
extern "C" void kernel_launch(void* const* d_in, const int* in_sizes, int n_in,
                              void* d_out, int out_size, void* d_ws, size_t ws_size,
                              hipStream_t stream)
{
  const float* resid = (const float*)d_in[0];
  const float* WQ   = (const float*)d_in[1];
  const float* WK   = (const float*)d_in[2];
  const float* WV   = (const float*)d_in[3];
  const float* WO   = (const float*)d_in[4];
  const float* bQ   = (const float*)d_in[5];
  const float* bK   = (const float*)d_in[6];
  const float* bV   = (const float*)d_in[7];
  const float* vk   = (const float*)d_in[8];
  const float* vv   = (const float*)d_in[9];
  const float* rsin = (const float*)d_in[10];
  const float* rcos = (const float*)d_in[11];

  char* ws = (char*)d_ws;
  __bf16* Rb  = (__bf16*)(ws);               // [4096][768]
  __bf16* Wt1 = (__bf16*)(ws + 6291456);     // [2304][768]
  __bf16* Wt2 = (__bf16*)(ws + 9830400);     // [768][768]
  __bf16* QKV = (__bf16*)(ws + 11010048);    // [4096][2304]
  __bf16* Qb  = (__bf16*)(ws + 29884416);    // [24][2048][64]
  __bf16* Kb  = (__bf16*)(ws + 36175872);    // [24][2112][64]
  __bf16* Vt  = (__bf16*)(ws + 42663936);    // [24][64][2112]
  __bf16* Zb  = (__bf16*)(ws + 49152000);    // [4096][768]

  prep_kernel<<<21504, 256, 0, stream>>>(resid, WQ, WK, WV, WO, Rb, Wt1, Wt2);
  gemm_bt<0><<<dim3(18, 32), 256, 0, stream>>>(Rb, Wt1, (void*)QKV, 4096, 2304, 768, 2304);
  qk_rotary<<<12672, 256, 0, stream>>>(QKV, bQ, bK, vk, rsin, rcos, Qb, Kb);
  v_trans<<<dim3(33, 24), 256, 0, stream>>>(QKV, bV, vv, Vt);
  attn_kernel<<<dim3(32, 24), 256, 0, stream>>>(Qb, Kb, Vt, Zb);
  gemm_bt<1><<<dim3(6, 32), 256, 0, stream>>>(Zb, Wt2, d_out, 4096, 768, 768, 768);
}

// Round 4
// 189.621 us; speedup vs baseline: 1.1231x; 1.1231x over previous
//
#include <hip/hip_runtime.h>

// ---------------- types / helpers ----------------
typedef __attribute__((ext_vector_type(8))) __bf16 bf16x8;
typedef __attribute__((ext_vector_type(4))) __bf16 bf16x4;
typedef __attribute__((ext_vector_type(4))) float  f32x4;

__device__ __forceinline__ void gld_lds16(const void* g, void* l) {
  __builtin_amdgcn_global_load_lds(
      (const __attribute__((address_space(1))) unsigned int*)g,
      (__attribute__((address_space(3))) unsigned int*)l, 16, 0, 0);
}

// Problem constants: B=2 S=2048 D=768 NQK=12 DQK=64 NOV=768 DOV=1 R=64 VKV=4
// SKV = 2052 (real+virtual keys), SKP = 2112 (padded to 33*64)

// ---------------- prep: bf16 conversions + weight transposes ----------------
// Rb  [4096][768] = resid (vec4); Wt1 [2304][768] = [Wq|Wk|Wv]^T; Wt2 [768][768] = Wo^T
__global__ __launch_bounds__(256) void prep_kernel(
    const float* __restrict__ resid, const float* __restrict__ WQ,
    const float* __restrict__ WK, const float* __restrict__ WV,
    const float* __restrict__ WO,
    __bf16* __restrict__ Rb, __bf16* __restrict__ Wt1, __bf16* __restrict__ Wt2)
{
  int t = blockIdx.x * 256 + threadIdx.x;
  if (t < 786432) {               // resid: 4 floats per thread
    f32x4 v = *(const f32x4*)(resid + (size_t)t * 4);
    bf16x4 o;
#pragma unroll
    for (int j = 0; j < 4; ++j) o[j] = (__bf16)v[j];
    *(bf16x4*)(Rb + (size_t)t * 4) = o;
    return;
  }
  t -= 786432;
  if (t < 1769472) {
    int nn = t / 768, k = t - nn * 768;
    float v;
    if (nn < 768)       v = WQ[(nn >> 6) * 49152 + k * 64 + (nn & 63)];
    else if (nn < 1536) v = WK[((nn - 768) >> 6) * 49152 + k * 64 + ((nn - 768) & 63)];
    else                v = WV[(nn - 1536) * 768 + k];
    Wt1[t] = (__bf16)v;
    return;
  }
  t -= 1769472;
  int nn = t / 768, k = t - nn * 768;
  Wt2[t] = (__bf16)WO[k * 768 + nn];
}

// ---------------- bf16 GEMM: C[M][N] = A[M][K] * Bt[N][K]^T ----------------
// 128x128 tile, BK=64, 4 waves, double-buffered LDS (2-phase prefetch),
// global_load_lds(16B), XOR-swizzled LDS ((row&7)<<4) via pre-swizzled source.
template<int OUTF>  // 0: bf16 out, 1: f32 out
__global__ __launch_bounds__(256) void gemm_bt(
    const __bf16* __restrict__ A, const __bf16* __restrict__ Bt,
    void* __restrict__ C, int M, int N, int K, int ldc)
{
  __shared__ __align__(16) char smem[65536];   // 2 bufs x (A 16KB + B 16KB)
  const int tid = threadIdx.x;
  const int l = tid & 63, wv = tid >> 6;
  const int wr = wv >> 1, wc = wv & 1;
  const int l15 = l & 15, lg = l >> 4;
  const int m0 = blockIdx.y * 128, n0 = blockIdx.x * 128;
  const int sw = (l15 & 7) << 4;

  auto stage = [&](int buf, int k0) {
    char* a_l = smem + buf * 32768;
    char* b_l = a_l + 16384;
#pragma unroll
    for (int c = 0; c < 4; ++c) {
      int i2 = c * 256 + tid;
      int row = i2 >> 3, slt = i2 & 7;
      gld_lds16(A + (size_t)(m0 + row) * K + k0 + ((slt ^ (row & 7)) * 8), a_l + i2 * 16);
    }
#pragma unroll
    for (int c = 0; c < 4; ++c) {
      int i2 = c * 256 + tid;
      int row = i2 >> 3, slt = i2 & 7;
      gld_lds16(Bt + (size_t)(n0 + row) * K + k0 + ((slt ^ (row & 7)) * 8), b_l + i2 * 16);
    }
  };

  f32x4 acc[4][4] = {};
  stage(0, 0);
  __syncthreads();
  int cur = 0;
  for (int k0 = 0; k0 < K; k0 += 64) {
    if (k0 + 64 < K) stage(cur ^ 1, k0 + 64);
    char* a_lds = smem + cur * 32768;
    char* b_lds = a_lds + 16384;
#pragma unroll
    for (int kk = 0; kk < 2; ++kk) {
      bf16x8 af[4], bfr[4];
#pragma unroll
      for (int i = 0; i < 4; ++i) {
        int mr = wr * 64 + i * 16 + l15;
        af[i]  = *(const bf16x8*)(a_lds + mr * 128 + ((lg * 16 + kk * 64) ^ sw));
        int nr = wc * 64 + i * 16 + l15;
        bfr[i] = *(const bf16x8*)(b_lds + nr * 128 + ((lg * 16 + kk * 64) ^ sw));
      }
#pragma unroll
      for (int i = 0; i < 4; ++i)
#pragma unroll
        for (int j = 0; j < 4; ++j)
          acc[i][j] = __builtin_amdgcn_mfma_f32_16x16x32_bf16(af[i], bfr[j], acc[i][j], 0, 0, 0);
    }
    __syncthreads();
    cur ^= 1;
  }
  // epilogue: D row=(lg*4+r), col=l15 per 16x16 frag
#pragma unroll
  for (int i = 0; i < 4; ++i)
#pragma unroll
    for (int j = 0; j < 4; ++j)
#pragma unroll
      for (int r = 0; r < 4; ++r) {
        int row = m0 + wr * 64 + i * 16 + lg * 4 + r;
        int col = n0 + wc * 64 + j * 16 + l15;
        if (OUTF) ((float*)C)[(size_t)row * ldc + col] = acc[i][j][r];
        else      ((__bf16*)C)[(size_t)row * ldc + col] = (__bf16)acc[i][j][r];
      }
}

// ---------------- rotary + Q/K layout (vectorized) ----------------
// Qb [24][2048][64] = rope(q + bQ)/8 ; Kb [24][2112][64] = rope(k + bK) | virtual_k | 0
// Thread handles 8 lower-half d's and their 8 upper-half partners for one (bh,s).
__global__ __launch_bounds__(256) void qk_rotary(
    const __bf16* __restrict__ qkv, const float* __restrict__ bQ,
    const float* __restrict__ bK, const float* __restrict__ vk,
    const float* __restrict__ rsin, const float* __restrict__ rcos,
    __bf16* __restrict__ Qb, __bf16* __restrict__ Kb)
{
  int t = blockIdx.x * 256 + threadIdx.x;
  if (t < 196608) {
    int d0 = (t & 3) * 8;          // 0,8,16,24  (lower half)
    int x = t >> 2;                // bh*2048 + s
    int bh = x >> 11, s = x & 2047;
    int b = bh / 12, h = bh - b * 12;
    const __bf16* rowp = qkv + ((size_t)(b * 2048 + s)) * 2304 + h * 64;
    bf16x8 ql = *(const bf16x8*)(rowp + d0);
    bf16x8 qu = *(const bf16x8*)(rowp + d0 + 32);
    bf16x8 kl = *(const bf16x8*)(rowp + 768 + d0);
    bf16x8 ku = *(const bf16x8*)(rowp + 768 + d0 + 32);
    const float* bql = bQ + h * 64 + d0;
    const float* bkl = bK + h * 64 + d0;
    const float* snp = rsin + s * 64 + d0;
    const float* csp = rcos + s * 64 + d0;
    f32x4 bq0 = *(const f32x4*)(bql),      bq1 = *(const f32x4*)(bql + 4);
    f32x4 bq2 = *(const f32x4*)(bql + 32), bq3 = *(const f32x4*)(bql + 36);
    f32x4 bk0 = *(const f32x4*)(bkl),      bk1 = *(const f32x4*)(bkl + 4);
    f32x4 bk2 = *(const f32x4*)(bkl + 32), bk3 = *(const f32x4*)(bkl + 36);
    f32x4 sl0 = *(const f32x4*)(snp),      sl1 = *(const f32x4*)(snp + 4);
    f32x4 su0 = *(const f32x4*)(snp + 32), su1 = *(const f32x4*)(snp + 36);
    f32x4 cl0 = *(const f32x4*)(csp),      cl1 = *(const f32x4*)(csp + 4);
    f32x4 cu0 = *(const f32x4*)(csp + 32), cu1 = *(const f32x4*)(csp + 36);
    bf16x8 qlo, quo, klo, kuo;
#pragma unroll
    for (int j = 0; j < 8; ++j) {
      float snl = (j < 4) ? sl0[j & 3] : sl1[j & 3];
      float csl = (j < 4) ? cl0[j & 3] : cl1[j & 3];
      float snu = (j < 4) ? su0[j & 3] : su1[j & 3];
      float csu = (j < 4) ? cu0[j & 3] : cu1[j & 3];
      float q1 = (float)ql[j] + ((j < 4) ? bq0[j & 3] : bq1[j & 3]);
      float q2 = (float)qu[j] + ((j < 4) ? bq2[j & 3] : bq3[j & 3]);
      float k1 = (float)kl[j] + ((j < 4) ? bk0[j & 3] : bk1[j & 3]);
      float k2 = (float)ku[j] + ((j < 4) ? bk2[j & 3] : bk3[j & 3]);
      qlo[j] = (__bf16)((q1 * csl - q2 * snl) * 0.125f);
      quo[j] = (__bf16)((q2 * csu + q1 * snu) * 0.125f);
      klo[j] = (__bf16)(k1 * csl - k2 * snl);
      kuo[j] = (__bf16)(k2 * csu + k1 * snu);
    }
    __bf16* qb = Qb + ((size_t)bh * 2048 + s) * 64;
    __bf16* kb = Kb + ((size_t)bh * 2112 + s) * 64;
    *(bf16x8*)(qb + d0) = qlo;  *(bf16x8*)(qb + d0 + 32) = quo;
    *(bf16x8*)(kb + d0) = klo;  *(bf16x8*)(kb + d0 + 32) = kuo;
    return;
  }
  t -= 196608;                    // K pad region: s in [2048,2112)
  if (t < 12288) {
    int d0 = (t & 7) * 8;
    int x = t >> 3;               // bh*64 + sp
    int bh = x >> 6, sp = x & 63;
    int h = bh % 12;
    bf16x8 o;
    if (sp < 4) {
      const float* vp = vk + ((size_t)sp * 12 + h) * 64 + d0;
      f32x4 v0 = *(const f32x4*)(vp), v1 = *(const f32x4*)(vp + 4);
#pragma unroll
      for (int j = 0; j < 8; ++j) o[j] = (__bf16)((j < 4) ? v0[j & 3] : v1[j & 3]);
    } else {
#pragma unroll
      for (int j = 0; j < 8; ++j) o[j] = (__bf16)0.0f;
    }
    *(bf16x8*)(Kb + ((size_t)bh * 2112 + 2048 + sp) * 64 + d0) = o;
  }
}

// ---------------- V transpose: Vt [24][64 dv][2112 s] (vectorized) ----------------
__global__ __launch_bounds__(256) void v_trans(
    const __bf16* __restrict__ qkv, const float* __restrict__ bV,
    const float* __restrict__ vv, __bf16* __restrict__ Vt)
{
  __shared__ float tile[64][65];
  int st = blockIdx.x, bh = blockIdx.y;
  int b = bh / 12, h = bh - b * 12;
  int tid = threadIdx.x;
#pragma unroll
  for (int c = 0; c < 2; ++c) {
    int chunk = c * 256 + tid;
    int srow = chunk >> 3, d0 = (chunk & 7) * 8;
    int s = st * 64 + srow;
    float vals[8];
    if (s < 2048) {
      bf16x8 v8 = *(const bf16x8*)(qkv + ((size_t)(b * 2048 + s)) * 2304 + 1536 + h * 64 + d0);
      const float* bvp = bV + h * 64 + d0;
      f32x4 b0 = *(const f32x4*)(bvp), b1 = *(const f32x4*)(bvp + 4);
#pragma unroll
      for (int j = 0; j < 8; ++j) vals[j] = (float)v8[j] + ((j < 4) ? b0[j & 3] : b1[j & 3]);
    } else if (s < 2052) {
      const float* vp = vv + (size_t)(s - 2048) * 768 + h * 64 + d0;
      f32x4 v0 = *(const f32x4*)(vp), v1 = *(const f32x4*)(vp + 4);
#pragma unroll
      for (int j = 0; j < 8; ++j) vals[j] = (j < 4) ? v0[j & 3] : v1[j & 3];
    } else {
#pragma unroll
      for (int j = 0; j < 8; ++j) vals[j] = 0.0f;
    }
#pragma unroll
    for (int j = 0; j < 8; ++j) tile[srow][d0 + j] = vals[j];
  }
  __syncthreads();
#pragma unroll
  for (int c = 0; c < 2; ++c) {
    int chunk = c * 256 + tid;
    int drow = chunk >> 3, s0 = (chunk & 7) * 8;
    bf16x8 o8;
#pragma unroll
    for (int j = 0; j < 8; ++j) o8[j] = (__bf16)tile[s0 + j][drow];
    *(bf16x8*)(Vt + ((size_t)bh * 64 + drow) * 2112 + st * 64 + s0) = o8;
  }
}

// ---------------- flash attention ----------------
// 1D grid 768: bh = idx%24 (24=3*8 -> each XCD sees 3 heads), qt = 31 - idx/24
// (longest blocks dispatch first). 4 waves x 16 queries, 64-key tiles,
// double-buffered K/V LDS with 2-phase prefetch (one barrier per tile).
__global__ __launch_bounds__(256) void attn_kernel(
    const __bf16* __restrict__ Qb, const __bf16* __restrict__ Kb,
    const __bf16* __restrict__ Vt, __bf16* __restrict__ Z)
{
  __shared__ __align__(16) char smem[40960];  // 2 x (K 8KB + V 8KB) + P 8KB
  char* p_lds = smem + 32768;
  const int tid = threadIdx.x;
  const int l = tid & 63, w = tid >> 6;
  const int l15 = l & 15, lg = l >> 4;
  const int idx = blockIdx.x;
  const int bh = idx % 24;
  const int qt = 31 - idx / 24;
  const int b = bh / 12, n = bh - b * 12;
  const int q16 = qt * 64 + w * 16;
  const int sw = (l15 & 7) << 4;
  const int qrow = w * 16 + l15;

  const __bf16* Kbase = Kb + (size_t)bh * 2112 * 64;
  const __bf16* Vbase = Vt + (size_t)bh * 64 * 2112;
  const int ntiles = qt + 2;

  auto stage = [&](int buf, int kt0) {
    char* k_l = smem + buf * 16384;
    char* v_l = k_l + 8192;
#pragma unroll
    for (int c = 0; c < 2; ++c) {
      int i2 = c * 256 + tid;
      int row = i2 >> 3, slt = i2 & 7;
      gld_lds16(Kbase + (kt0 + row) * 64 + ((slt ^ (row & 7)) * 8), k_l + i2 * 16);
    }
#pragma unroll
    for (int c = 0; c < 2; ++c) {
      int i2 = c * 256 + tid;
      int row = i2 >> 3, slt = i2 & 7;
      gld_lds16(Vbase + row * 2112 + kt0 + ((slt ^ (row & 7)) * 8), v_l + i2 * 16);
    }
  };

  stage(0, 0);

  const __bf16* qp = Qb + ((size_t)bh * 2048 + q16 + l15) * 64 + lg * 8;
  const bf16x8 qa0 = *(const bf16x8*)qp;          // Q[q][0..31] B-frag
  const bf16x8 qa1 = *(const bf16x8*)(qp + 32);   // Q[q][32..63]

  f32x4 o[4] = {};
  float mrun = -1e30f, lrun = 0.0f;
  __syncthreads();

  int cur = 0;
  for (int kt = 0; kt < ntiles; ++kt) {
    const int kt0 = kt * 64;
    if (kt + 1 < ntiles) stage(cur ^ 1, kt0 + 64);
    char* k_lds = smem + cur * 16384;
    char* v_lds = k_lds + 8192;

    if (kt0 <= q16 + 19) {   // wave has at least one visible key in this tile
      f32x4 sfr[4];
#pragma unroll
      for (int kb = 0; kb < 4; ++kb) {
        int krow = kb * 16 + l15;
        f32x4 a = {};
        bf16x8 ka0 = *(const bf16x8*)(k_lds + krow * 128 + ((lg * 16) ^ sw));
        bf16x8 ka1 = *(const bf16x8*)(k_lds + krow * 128 + ((lg * 16 + 64) ^ sw));
        a = __builtin_amdgcn_mfma_f32_16x16x32_bf16(ka0, qa0, a, 0, 0, 0);
        a = __builtin_amdgcn_mfma_f32_16x16x32_bf16(ka1, qa1, a, 0, 0, 0);
        sfr[kb] = a;
      }
      if (kt >= qt) {  // masked tiles: key visible iff k <= q+4 && k < 2052
        int qlim = q16 + l15 + 4;
#pragma unroll
        for (int kb = 0; kb < 4; ++kb)
#pragma unroll
          for (int r = 0; r < 4; ++r) {
            int kg = kt0 + kb * 16 + lg * 4 + r;
            if (kg > qlim || kg >= 2052) sfr[kb][r] = -1e30f;
          }
      }
      float tmax = -1e30f;
#pragma unroll
      for (int kb = 0; kb < 4; ++kb)
#pragma unroll
        for (int r = 0; r < 4; ++r) tmax = fmaxf(tmax, sfr[kb][r]);
      tmax = fmaxf(tmax, __shfl_xor(tmax, 16));
      tmax = fmaxf(tmax, __shfl_xor(tmax, 32));
      float mnew = fmaxf(mrun, tmax);
      float fsc = __expf(mrun - mnew);
      float rsum = 0.0f;
#pragma unroll
      for (int kb = 0; kb < 4; ++kb) {
        bf16x4 pv;
#pragma unroll
        for (int r = 0; r < 4; ++r) {
          float p = __expf(sfr[kb][r] - mnew);
          rsum += p;
          pv[r] = (__bf16)p;
        }
        *(bf16x4*)(p_lds + qrow * 128 + ((kb * 32 + lg * 8) ^ sw)) = pv;
      }
      rsum += __shfl_xor(rsum, 16);
      rsum += __shfl_xor(rsum, 32);
      lrun = lrun * fsc + rsum;
      mrun = mnew;
      f32x4 fv;
#pragma unroll
      for (int r = 0; r < 4; ++r) fv[r] = __shfl(fsc, lg * 4 + r);  // O rows are lg*4+r
#pragma unroll
      for (int dv = 0; dv < 4; ++dv) o[dv] *= fv;
#pragma unroll
      for (int kblk = 0; kblk < 2; ++kblk) {
        bf16x8 pa = *(const bf16x8*)(p_lds + qrow * 128 + ((kblk * 64 + lg * 16) ^ sw));
#pragma unroll
        for (int dv = 0; dv < 4; ++dv) {
          int vrow = dv * 16 + l15;
          bf16x8 vb = *(const bf16x8*)(v_lds + vrow * 128 + ((kblk * 64 + lg * 16) ^ sw));
          o[dv] = __builtin_amdgcn_mfma_f32_16x16x32_bf16(pa, vb, o[dv], 0, 0, 0);
        }
      }
    }
    __syncthreads();   // drains this iter's prefetch (vmcnt 0) + protects buffers
    cur ^= 1;
  }
  float linv = 1.0f / lrun;
  f32x4 lv;
#pragma unroll
  for (int r = 0; r < 4; ++r) lv[r] = __shfl(linv, lg * 4 + r);
  __bf16* zbase = Z + ((size_t)b * 2048 + q16) * 768 + n * 64;
#pragma unroll
  for (int dv = 0; dv < 4; ++dv)
#pragma unroll
    for (int r = 0; r < 4; ++r)
      zbase[(lg * 4 + r) * 768 + dv * 16 + l15] = (__bf16)(o[dv][r] * lv[r]);
}

// ---------------- launch ----------------
extern "C" void kernel_launch(void* const* d_in, const int* in_sizes, int n_in,
                              void* d_out, int out_size, void* d_ws, size_t ws_size,
                              hipStream_t stream)
{
  const float* resid = (const float*)d_in[0];
  const float* WQ   = (const float*)d_in[1];
  const float* WK   = (const float*)d_in[2];
  const float* WV   = (const float*)d_in[3];
  const float* WO   = (const float*)d_in[4];
  const float* bQ   = (const float*)d_in[5];
  const float* bK   = (const float*)d_in[6];
  const float* bV   = (const float*)d_in[7];
  const float* vk   = (const float*)d_in[8];
  const float* vv   = (const float*)d_in[9];
  const float* rsin = (const float*)d_in[10];
  const float* rcos = (const float*)d_in[11];

  char* ws = (char*)d_ws;
  __bf16* Rb  = (__bf16*)(ws);               // [4096][768]
  __bf16* Wt1 = (__bf16*)(ws + 6291456);     // [2304][768]
  __bf16* Wt2 = (__bf16*)(ws + 9830400);     // [768][768]
  __bf16* QKV = (__bf16*)(ws + 11010048);    // [4096][2304]
  __bf16* Qb  = (__bf16*)(ws + 29884416);    // [24][2048][64]
  __bf16* Kb  = (__bf16*)(ws + 36175872);    // [24][2112][64]
  __bf16* Vt  = (__bf16*)(ws + 42663936);    // [24][64][2112]
  __bf16* Zb  = (__bf16*)(ws + 49152000);    // [4096][768]

  prep_kernel<<<12288, 256, 0, stream>>>(resid, WQ, WK, WV, WO, Rb, Wt1, Wt2);
  gemm_bt<0><<<dim3(18, 32), 256, 0, stream>>>(Rb, Wt1, (void*)QKV, 4096, 2304, 768, 2304);
  qk_rotary<<<816, 256, 0, stream>>>(QKV, bQ, bK, vk, rsin, rcos, Qb, Kb);
  v_trans<<<dim3(33, 24), 256, 0, stream>>>(QKV, bV, vv, Vt);
  attn_kernel<<<768, 256, 0, stream>>>(Qb, Kb, Vt, Zb);
  gemm_bt<1><<<dim3(6, 32), 256, 0, stream>>>(Zb, Wt2, d_out, 4096, 768, 768, 768);
}

// Round 7
// 185.415 us; speedup vs baseline: 1.1486x; 1.0227x over previous
//
#include <hip/hip_runtime.h>

// ---------------- types / helpers ----------------
typedef __attribute__((ext_vector_type(8))) __bf16 bf16x8;
typedef __attribute__((ext_vector_type(4))) __bf16 bf16x4;
typedef __attribute__((ext_vector_type(4))) float  f32x4;

__device__ __forceinline__ void gld_lds16(const void* g, void* l) {
  __builtin_amdgcn_global_load_lds(
      (const __attribute__((address_space(1))) unsigned int*)g,
      (__attribute__((address_space(3))) unsigned int*)l, 16, 0, 0);
}

// Problem constants: B=2 S=2048 D=768 NQK=12 DQK=64 NOV=768 DOV=1 R=64 VKV=4
// SKV = 2052 (real+virtual keys), SKP = 2112 (padded to 33*64)
// Softmax runs in BASE-2 domain: Q is pre-scaled by 0.125*log2(e).
#define QSCALE 0.18033688011112042f

// ---------------- prep: resid + WV bf16 conversions ----------------
__global__ __launch_bounds__(256) void prep_kernel(
    const float* __restrict__ resid, const float* __restrict__ WV,
    __bf16* __restrict__ Rb, __bf16* __restrict__ Wt1)
{
  int t = blockIdx.x * 256 + threadIdx.x;
  if (t < 786432) {               // resid: 4 floats per thread
    f32x4 v = *(const f32x4*)(resid + (size_t)t * 4);
    bf16x4 o;
#pragma unroll
    for (int j = 0; j < 4; ++j) o[j] = (__bf16)v[j];
    *(bf16x4*)(Rb + (size_t)t * 4) = o;
    return;
  }
  t -= 786432;
  if (t < 73728) {                // WV -> Wt1 rows [1536,2304): straight copy, vec8
    const float* vp = WV + (size_t)t * 8;
    f32x4 v0 = *(const f32x4*)vp, v1 = *(const f32x4*)(vp + 4);
    bf16x8 o;
#pragma unroll
    for (int j = 0; j < 8; ++j) o[j] = (__bf16)((j < 4) ? v0[j & 3] : v1[j & 3]);
    *(bf16x8*)(Wt1 + (size_t)1536 * 768 + (size_t)t * 8) = o;
  }
}

// ---------------- LDS-tiled weight transposes ----------------
// grid 432: [0,144) WQ -> Wt1 rows [0,768); [144,288) WK -> rows [768,1536);
// [288,432) WO^T -> Wt2. 64x64 f32 tile via LDS, both sides coalesced.
__global__ __launch_bounds__(256) void wtrans_kernel(
    const float* __restrict__ WQ, const float* __restrict__ WK,
    const float* __restrict__ WO,
    __bf16* __restrict__ Wt1, __bf16* __restrict__ Wt2)
{
  __shared__ float tile[64][65];
  int g = blockIdx.x, tid = threadIdx.x;
  const float* src; __bf16* dst;
  int sld, dld, r0, c0, drow0, dcol0;
  if (g < 288) {                 // WQ / WK: per head [768 k][64 d] -> rows h*64+d, col k
    const float* W = (g < 144) ? WQ : WK;
    int gg = g % 144;
    int h = gg / 12, kt = gg - h * 12;
    src = W + (size_t)h * 49152; sld = 64; r0 = kt * 64; c0 = 0;
    dst = Wt1; dld = 768;
    drow0 = ((g < 144) ? 0 : 768) + h * 64; dcol0 = kt * 64;
  } else {                       // WO [768 nov][768 m] -> Wt2[m][nov]
    int gg = g - 288;
    int rt = gg / 12, ct = gg - rt * 12;
    src = WO; sld = 768; r0 = rt * 64; c0 = ct * 64;
    dst = Wt2; dld = 768; drow0 = ct * 64; dcol0 = rt * 64;
  }
#pragma unroll
  for (int c = 0; c < 4; ++c) {  // load 64 rows x 64 cols f32 (vec4)
    int li = c * 256 + tid;
    int r = li >> 4, cc = (li & 15) * 4;
    f32x4 v = *(const f32x4*)(src + (size_t)(r0 + r) * sld + c0 + cc);
#pragma unroll
    for (int j = 0; j < 4; ++j) tile[r][cc + j] = v[j];
  }
  __syncthreads();
#pragma unroll
  for (int c = 0; c < 2; ++c) {  // store transposed, vec8 bf16
    int li = c * 256 + tid;
    int cc = li >> 3, rr = (li & 7) * 8;
    bf16x8 o;
#pragma unroll
    for (int j = 0; j < 8; ++j) o[j] = (__bf16)tile[rr + j][cc];
    *(bf16x8*)(dst + (size_t)(drow0 + cc) * dld + dcol0 + rr) = o;
  }
}

// ---------------- bf16 GEMM: C[M][N] = A[M][K] * Bt[N][K]^T ----------------
// 128xBN tile, BK=64, 4 waves, double-buffered LDS (2-phase prefetch),
// global_load_lds(16B), XOR-swizzled LDS ((row&7)<<4) via pre-swizzled source.
template<int OUTF, int BN>  // OUTF 0: bf16 out, 1: f32 out; BN in {128, 64}
__global__ __launch_bounds__(256) void gemm_bt(
    const __bf16* __restrict__ A, const __bf16* __restrict__ Bt,
    void* __restrict__ C, int M, int N, int K, int ldc)
{
  constexpr int LDSB = BN * 128;
  constexpr int BUF  = 16384 + LDSB;
  constexpr int BSTG = BN / 32;
  constexpr int IM   = (BN == 128) ? 4 : 2;
  __shared__ __align__(16) char smem[2 * BUF];
  const int tid = threadIdx.x;
  const int l = tid & 63, wv = tid >> 6;
  const int l15 = l & 15, lg = l >> 4;
  const int wmb = (BN == 128) ? (wv >> 1) * 64 : wv * 32;
  const int wnb = (BN == 128) ? (wv & 1) * 64 : 0;
  const int m0 = blockIdx.y * 128, n0 = blockIdx.x * BN;
  const int sw = (l15 & 7) << 4;

  auto stage = [&](int buf, int k0) {
    char* a_l = smem + buf * BUF;
    char* b_l = a_l + 16384;
#pragma unroll
    for (int c = 0; c < 4; ++c) {
      int i2 = c * 256 + tid;
      int row = i2 >> 3, slt = i2 & 7;
      gld_lds16(A + (size_t)(m0 + row) * K + k0 + ((slt ^ (row & 7)) * 8), a_l + i2 * 16);
    }
#pragma unroll
    for (int c = 0; c < BSTG; ++c) {
      int i2 = c * 256 + tid;
      int row = i2 >> 3, slt = i2 & 7;
      gld_lds16(Bt + (size_t)(n0 + row) * K + k0 + ((slt ^ (row & 7)) * 8), b_l + i2 * 16);
    }
  };

  f32x4 acc[IM][4] = {};
  stage(0, 0);
  __syncthreads();
  int cur = 0;
  for (int k0 = 0; k0 < K; k0 += 64) {
    if (k0 + 64 < K) stage(cur ^ 1, k0 + 64);
    char* a_lds = smem + cur * BUF;
    char* b_lds = a_lds + 16384;
#pragma unroll
    for (int kk = 0; kk < 2; ++kk) {
      bf16x8 af[IM], bfr[4];
#pragma unroll
      for (int i = 0; i < IM; ++i) {
        int mr = wmb + i * 16 + l15;
        af[i] = *(const bf16x8*)(a_lds + mr * 128 + ((lg * 16 + kk * 64) ^ sw));
      }
#pragma unroll
      for (int j = 0; j < 4; ++j) {
        int nr = wnb + j * 16 + l15;
        bfr[j] = *(const bf16x8*)(b_lds + nr * 128 + ((lg * 16 + kk * 64) ^ sw));
      }
#pragma unroll
      for (int i = 0; i < IM; ++i)
#pragma unroll
        for (int j = 0; j < 4; ++j)
          acc[i][j] = __builtin_amdgcn_mfma_f32_16x16x32_bf16(af[i], bfr[j], acc[i][j], 0, 0, 0);
    }
    __syncthreads();
    cur ^= 1;
  }
#pragma unroll
  for (int i = 0; i < IM; ++i)
#pragma unroll
    for (int j = 0; j < 4; ++j)
#pragma unroll
      for (int r = 0; r < 4; ++r) {
        int row = m0 + wmb + i * 16 + lg * 4 + r;
        int col = n0 + wnb + j * 16 + l15;
        if (OUTF) ((float*)C)[(size_t)row * ldc + col] = acc[i][j][r];
        else      ((__bf16*)C)[(size_t)row * ldc + col] = (__bf16)acc[i][j][r];
      }
}

// ---------------- rotary + Q/K layout (vectorized) ----------------
// Qb = rope(q+bQ)*QSCALE (base-2 softmax domain); Kb = rope(k+bK) | virtual_k | 0
__global__ __launch_bounds__(256) void qk_rotary(
    const __bf16* __restrict__ qkv, const float* __restrict__ bQ,
    const float* __restrict__ bK, const float* __restrict__ vk,
    const float* __restrict__ rsin, const float* __restrict__ rcos,
    __bf16* __restrict__ Qb, __bf16* __restrict__ Kb)
{
  int t = blockIdx.x * 256 + threadIdx.x;
  if (t < 196608) {
    int d0 = (t & 3) * 8;          // 0,8,16,24  (lower half)
    int x = t >> 2;                // bh*2048 + s
    int bh = x >> 11, s = x & 2047;
    int b = bh / 12, h = bh - b * 12;
    const __bf16* rowp = qkv + ((size_t)(b * 2048 + s)) * 2304 + h * 64;
    bf16x8 ql = *(const bf16x8*)(rowp + d0);
    bf16x8 qu = *(const bf16x8*)(rowp + d0 + 32);
    bf16x8 kl = *(const bf16x8*)(rowp + 768 + d0);
    bf16x8 ku = *(const bf16x8*)(rowp + 768 + d0 + 32);
    const float* bql = bQ + h * 64 + d0;
    const float* bkl = bK + h * 64 + d0;
    const float* snp = rsin + s * 64 + d0;
    const float* csp = rcos + s * 64 + d0;
    f32x4 bq0 = *(const f32x4*)(bql),      bq1 = *(const f32x4*)(bql + 4);
    f32x4 bq2 = *(const f32x4*)(bql + 32), bq3 = *(const f32x4*)(bql + 36);
    f32x4 bk0 = *(const f32x4*)(bkl),      bk1 = *(const f32x4*)(bkl + 4);
    f32x4 bk2 = *(const f32x4*)(bkl + 32), bk3 = *(const f32x4*)(bkl + 36);
    f32x4 sl0 = *(const f32x4*)(snp),      sl1 = *(const f32x4*)(snp + 4);
    f32x4 su0 = *(const f32x4*)(snp + 32), su1 = *(const f32x4*)(snp + 36);
    f32x4 cl0 = *(const f32x4*)(csp),      cl1 = *(const f32x4*)(csp + 4);
    f32x4 cu0 = *(const f32x4*)(csp + 32), cu1 = *(const f32x4*)(csp + 36);
    bf16x8 qlo, quo, klo, kuo;
#pragma unroll
    for (int j = 0; j < 8; ++j) {
      float snl = (j < 4) ? sl0[j & 3] : sl1[j & 3];
      float csl = (j < 4) ? cl0[j & 3] : cl1[j & 3];
      float snu = (j < 4) ? su0[j & 3] : su1[j & 3];
      float csu = (j < 4) ? cu0[j & 3] : cu1[j & 3];
      float q1 = (float)ql[j] + ((j < 4) ? bq0[j & 3] : bq1[j & 3]);
      float q2 = (float)qu[j] + ((j < 4) ? bq2[j & 3] : bq3[j & 3]);
      float k1 = (float)kl[j] + ((j < 4) ? bk0[j & 3] : bk1[j & 3]);
      float k2 = (float)ku[j] + ((j < 4) ? bk2[j & 3] : bk3[j & 3]);
      qlo[j] = (__bf16)((q1 * csl - q2 * snl) * QSCALE);
      quo[j] = (__bf16)((q2 * csu + q1 * snu) * QSCALE);
      klo[j] = (__bf16)(k1 * csl - k2 * snl);
      kuo[j] = (__bf16)(k2 * csu + k1 * snu);
    }
    __bf16* qb = Qb + ((size_t)bh * 2048 + s) * 64;
    __bf16* kb = Kb + ((size_t)bh * 2112 + s) * 64;
    *(bf16x8*)(qb + d0) = qlo;  *(bf16x8*)(qb + d0 + 32) = quo;
    *(bf16x8*)(kb + d0) = klo;  *(bf16x8*)(kb + d0 + 32) = kuo;
    return;
  }
  t -= 196608;                    // K pad region: s in [2048,2112)
  if (t < 12288) {
    int d0 = (t & 7) * 8;
    int x = t >> 3;               // bh*64 + sp
    int bh = x >> 6, sp = x & 63;
    int h = bh % 12;
    bf16x8 o;
    if (sp < 4) {
      const float* vp = vk + ((size_t)sp * 12 + h) * 64 + d0;
      f32x4 v0 = *(const f32x4*)(vp), v1 = *(const f32x4*)(vp + 4);
#pragma unroll
      for (int j = 0; j < 8; ++j) o[j] = (__bf16)((j < 4) ? v0[j & 3] : v1[j & 3]);
    } else {
#pragma unroll
      for (int j = 0; j < 8; ++j) o[j] = (__bf16)0.0f;
    }
    *(bf16x8*)(Kb + ((size_t)bh * 2112 + 2048 + sp) * 64 + d0) = o;
  }
}

// ---------------- V transpose: Vt [24][64 dv][2112 s] (vectorized) ----------------
__global__ __launch_bounds__(256) void v_trans(
    const __bf16* __restrict__ qkv, const float* __restrict__ bV,
    const float* __restrict__ vv, __bf16* __restrict__ Vt)
{
  __shared__ float tile[64][65];
  int st = blockIdx.x, bh = blockIdx.y;
  int b = bh / 12, h = bh - b * 12;
  int tid = threadIdx.x;
#pragma unroll
  for (int c = 0; c < 2; ++c) {
    int chunk = c * 256 + tid;
    int srow = chunk >> 3, d0 = (chunk & 7) * 8;
    int s = st * 64 + srow;
    float vals[8];
    if (s < 2048) {
      bf16x8 v8 = *(const bf16x8*)(qkv + ((size_t)(b * 2048 + s)) * 2304 + 1536 + h * 64 + d0);
      const float* bvp = bV + h * 64 + d0;
      f32x4 b0 = *(const f32x4*)(bvp), b1 = *(const f32x4*)(bvp + 4);
#pragma unroll
      for (int j = 0; j < 8; ++j) vals[j] = (float)v8[j] + ((j < 4) ? b0[j & 3] : b1[j & 3]);
    } else if (s < 2052) {
      const float* vp = vv + (size_t)(s - 2048) * 768 + h * 64 + d0;
      f32x4 v0 = *(const f32x4*)(vp), v1 = *(const f32x4*)(vp + 4);
#pragma unroll
      for (int j = 0; j < 8; ++j) vals[j] = (j < 4) ? v0[j & 3] : v1[j & 3];
    } else {
#pragma unroll
      for (int j = 0; j < 8; ++j) vals[j] = 0.0f;
    }
#pragma unroll
    for (int j = 0; j < 8; ++j) tile[srow][d0 + j] = vals[j];
  }
  __syncthreads();
#pragma unroll
  for (int c = 0; c < 2; ++c) {
    int chunk = c * 256 + tid;
    int drow = chunk >> 3, s0 = (chunk & 7) * 8;
    bf16x8 o8;
#pragma unroll
    for (int j = 0; j < 8; ++j) o8[j] = (__bf16)tile[s0 + j][drow];
    *(bf16x8*)(Vt + ((size_t)bh * 64 + drow) * 2112 + st * 64 + s0) = o8;
  }
}

// ---------------- flash attention, split-K (flash-decoding) ----------------
// Grid 2016 = 24 bh * 84 (qt,split) pairs. Pairs enumerated qt=31..0 (longest
// first), each split covers <=8 key-tiles (512 keys). Blocks write UNNORMALIZED
// partials: O bf16 [64q][64dv], m/l f32 (base-2 domain). attn_merge combines.
__global__ __launch_bounds__(256) void attn_kernel(
    const __bf16* __restrict__ Qb, const __bf16* __restrict__ Kb,
    const __bf16* __restrict__ Vt, __bf16* __restrict__ Opart,
    float* __restrict__ ML)
{
  __shared__ __align__(16) char smem[40960];  // 2 x (K 8KB + V 8KB) + P 8KB
  char* p_lds = smem + 32768;
  const int tid = threadIdx.x;
  const int l = tid & 63, w = tid >> 6;
  const int l15 = l & 15, lg = l >> 4;
  const int idx = blockIdx.x;
  const int bh = idx % 24;           // 24 = 3*8 -> 3 heads per XCD
  int pidx = idx / 24;               // 0..83
  int qt = 31, rem = pidx;
  for (;;) { int c = (qt + 9) >> 3; if (rem < c) break; rem -= c; --qt; }
  const int ts = rem * 8;
  const int te = min(ts + 8, qt + 2);
  const int slot = bh * 84 + pidx;
  const int q16 = qt * 64 + w * 16;
  const int sw = (l15 & 7) << 4;
  const int qrow = w * 16 + l15;

  const __bf16* Kbase = Kb + (size_t)bh * 2112 * 64;
  const __bf16* Vbase = Vt + (size_t)bh * 64 * 2112;

  auto stage = [&](int buf, int kt0) {
    char* k_l = smem + buf * 16384;
    char* v_l = k_l + 8192;
#pragma unroll
    for (int c = 0; c < 2; ++c) {
      int i2 = c * 256 + tid;
      int row = i2 >> 3, slt = i2 & 7;
      gld_lds16(Kbase + (kt0 + row) * 64 + ((slt ^ (row & 7)) * 8), k_l + i2 * 16);
    }
#pragma unroll
    for (int c = 0; c < 2; ++c) {
      int i2 = c * 256 + tid;
      int row = i2 >> 3, slt = i2 & 7;
      gld_lds16(Vbase + row * 2112 + kt0 + ((slt ^ (row & 7)) * 8), v_l + i2 * 16);
    }
  };

  stage(0, ts * 64);

  const __bf16* qp = Qb + ((size_t)bh * 2048 + q16 + l15) * 64 + lg * 8;
  const bf16x8 qa0 = *(const bf16x8*)qp;          // Q[q][0..31] B-frag
  const bf16x8 qa1 = *(const bf16x8*)(qp + 32);   // Q[q][32..63]

  f32x4 o[4] = {};
  float mrun = -1e30f, lrun = 0.0f;
  __syncthreads();

  int cur = 0;
  for (int kt = ts; kt < te; ++kt) {
    const int kt0 = kt * 64;
    if (kt + 1 < te) stage(cur ^ 1, kt0 + 64);
    char* k_lds = smem + cur * 16384;
    char* v_lds = k_lds + 8192;

    if (kt0 <= q16 + 19) {   // wave has at least one visible key in this tile
      f32x4 sfr[4];
#pragma unroll
      for (int kb = 0; kb < 4; ++kb) {
        int krow = kb * 16 + l15;
        f32x4 a = {};
        bf16x8 ka0 = *(const bf16x8*)(k_lds + krow * 128 + ((lg * 16) ^ sw));
        bf16x8 ka1 = *(const bf16x8*)(k_lds + krow * 128 + ((lg * 16 + 64) ^ sw));
        a = __builtin_amdgcn_mfma_f32_16x16x32_bf16(ka0, qa0, a, 0, 0, 0);
        a = __builtin_amdgcn_mfma_f32_16x16x32_bf16(ka1, qa1, a, 0, 0, 0);
        sfr[kb] = a;
      }
      if (kt >= qt) {  // masked tiles: key visible iff k <= q+4 && k < 2052
        int qlim = q16 + l15 + 4;
#pragma unroll
        for (int kb = 0; kb < 4; ++kb)
#pragma unroll
          for (int r = 0; r < 4; ++r) {
            int kg = kt0 + kb * 16 + lg * 4 + r;
            if (kg > qlim || kg >= 2052) sfr[kb][r] = -1e30f;
          }
      }
      float tmax = -1e30f;
#pragma unroll
      for (int kb = 0; kb < 4; ++kb)
#pragma unroll
        for (int r = 0; r < 4; ++r) tmax = fmaxf(tmax, sfr[kb][r]);
      tmax = fmaxf(tmax, __shfl_xor(tmax, 16));
      tmax = fmaxf(tmax, __shfl_xor(tmax, 32));
      float mnew = fmaxf(mrun, tmax);
      int needresc = __any(mnew > mrun);
      float fsc = exp2f(mrun - mnew);
      float rsum = 0.0f;
#pragma unroll
      for (int kb = 0; kb < 4; ++kb) {
        bf16x4 pv;
#pragma unroll
        for (int r = 0; r < 4; ++r) {
          float p = exp2f(sfr[kb][r] - mnew);
          rsum += p;
          pv[r] = (__bf16)p;
        }
        *(bf16x4*)(p_lds + qrow * 128 + ((kb * 32 + lg * 8) ^ sw)) = pv;
      }
      rsum += __shfl_xor(rsum, 16);
      rsum += __shfl_xor(rsum, 32);
      lrun = lrun * fsc + rsum;
      mrun = mnew;
      if (needresc) {
        f32x4 fv;
#pragma unroll
        for (int r = 0; r < 4; ++r) fv[r] = __shfl(fsc, lg * 4 + r);  // O rows are lg*4+r
#pragma unroll
        for (int dv = 0; dv < 4; ++dv) o[dv] *= fv;
      }
#pragma unroll
      for (int kblk = 0; kblk < 2; ++kblk) {
        bf16x8 pa = *(const bf16x8*)(p_lds + qrow * 128 + ((kblk * 64 + lg * 16) ^ sw));
#pragma unroll
        for (int dv = 0; dv < 4; ++dv) {
          int vrow = dv * 16 + l15;
          bf16x8 vb = *(const bf16x8*)(v_lds + vrow * 128 + ((kblk * 64 + lg * 16) ^ sw));
          o[dv] = __builtin_amdgcn_mfma_f32_16x16x32_bf16(pa, vb, o[dv], 0, 0, 0);
        }
      }
    }
    __syncthreads();   // drains this iter's prefetch + protects buffers
    cur ^= 1;
  }
  // partial epilogue: unnormalized O (bf16), m/l (f32, base-2 domain)
  if (lg == 0) {
    ML[slot * 128 + qrow] = mrun;
    ML[slot * 128 + 64 + qrow] = lrun;
  }
  __bf16* op = Opart + (size_t)slot * 4096;
#pragma unroll
  for (int dv = 0; dv < 4; ++dv)
#pragma unroll
    for (int r = 0; r < 4; ++r)
      op[(w * 16 + lg * 4 + r) * 64 + dv * 16 + l15] = (__bf16)o[dv][r];
}

// ---------------- merge split-K partials -> Z ----------------
// grid 768 = 24 bh * 32 qt. Exact softmax combine in base-2 domain.
__global__ __launch_bounds__(256) void attn_merge(
    const __bf16* __restrict__ Opart, const float* __restrict__ ML,
    __bf16* __restrict__ Z)
{
  const int idx = blockIdx.x;
  const int bh = idx % 24, qt = idx / 24;
  const int b = bh / 12, n = bh - b * 12;
  int pbase = 0;
  for (int q2 = 31; q2 > qt; --q2) pbase += (q2 + 9) >> 3;
  const int ns = (qt + 9) >> 3;
  const int t = threadIdx.x;
  const int q = t >> 2, c0 = (t & 3) * 16;

  float M = -1e30f;
  for (int s = 0; s < ns; ++s)
    M = fmaxf(M, ML[(bh * 84 + pbase + s) * 128 + q]);
  float L = 0.0f;
  float acc[16] = {};
  for (int s = 0; s < ns; ++s) {
    int slot = bh * 84 + pbase + s;
    float ms = ML[slot * 128 + q], ls = ML[slot * 128 + 64 + q];
    float wgt = exp2f(ms - M);
    L += ls * wgt;
    const __bf16* op = Opart + (size_t)slot * 4096 + q * 64 + c0;
    bf16x8 o0 = *(const bf16x8*)op, o1 = *(const bf16x8*)(op + 8);
#pragma unroll
    for (int j = 0; j < 8; ++j) {
      acc[j]     += wgt * (float)o0[j];
      acc[8 + j] += wgt * (float)o1[j];
    }
  }
  float inv = 1.0f / L;
  bf16x8 z0, z1;
#pragma unroll
  for (int j = 0; j < 8; ++j) {
    z0[j] = (__bf16)(acc[j] * inv);
    z1[j] = (__bf16)(acc[8 + j] * inv);
  }
  __bf16* zp = Z + ((size_t)(b * 2048 + qt * 64 + q)) * 768 + n * 64 + c0;
  *(bf16x8*)zp = z0;
  *(bf16x8*)(zp + 8) = z1;
}

// ---------------- launch ----------------
extern "C" void kernel_launch(void* const* d_in, const int* in_sizes, int n_in,
                              void* d_out, int out_size, void* d_ws, size_t ws_size,
                              hipStream_t stream)
{
  const float* resid = (const float*)d_in[0];
  const float* WQ   = (const float*)d_in[1];
  const float* WK   = (const float*)d_in[2];
  const float* WV   = (const float*)d_in[3];
  const float* WO   = (const float*)d_in[4];
  const float* bQ   = (const float*)d_in[5];
  const float* bK   = (const float*)d_in[6];
  const float* bV   = (const float*)d_in[7];
  const float* vk   = (const float*)d_in[8];
  const float* vv   = (const float*)d_in[9];
  const float* rsin = (const float*)d_in[10];
  const float* rcos = (const float*)d_in[11];

  char* ws = (char*)d_ws;
  __bf16* Rb  = (__bf16*)(ws);               // [4096][768]
  __bf16* Wt1 = (__bf16*)(ws + 6291456);     // [2304][768]
  __bf16* Wt2 = (__bf16*)(ws + 9830400);     // [768][768]
  __bf16* QKV = (__bf16*)(ws + 11010048);    // [4096][2304]  (dead after v_trans)
  __bf16* Qb  = (__bf16*)(ws + 29884416);    // [24][2048][64]
  __bf16* Kb  = (__bf16*)(ws + 36175872);    // [24][2112][64]
  __bf16* Vt  = (__bf16*)(ws + 42663936);    // [24][64][2112]
  __bf16* Zb  = (__bf16*)(ws + 49152000);    // [4096][768]
  // split-K partials OVERLAY the dead QKV region (16.5MB + 1MB < 18.9MB)
  __bf16* Opart = (__bf16*)(ws + 11010048);          // 2016 x [64][64] bf16
  float*  MLp   = (float*)(ws + 11010048 + 16515072); // 2016 x 128 f32

  prep_kernel<<<3360, 256, 0, stream>>>(resid, WV, Rb, Wt1);
  wtrans_kernel<<<432, 256, 0, stream>>>(WQ, WK, WO, Wt1, Wt2);
  gemm_bt<0, 128><<<dim3(18, 32), 256, 0, stream>>>(Rb, Wt1, (void*)QKV, 4096, 2304, 768, 2304);
  qk_rotary<<<816, 256, 0, stream>>>(QKV, bQ, bK, vk, rsin, rcos, Qb, Kb);
  v_trans<<<dim3(33, 24), 256, 0, stream>>>(QKV, bV, vv, Vt);
  attn_kernel<<<2016, 256, 0, stream>>>(Qb, Kb, Vt, Opart, MLp);
  attn_merge<<<768, 256, 0, stream>>>(Opart, MLp, Zb);
  gemm_bt<1, 64><<<dim3(12, 32), 256, 0, stream>>>(Zb, Wt2, d_out, 4096, 768, 768, 768);
}

// Round 8
// 183.842 us; speedup vs baseline: 1.1584x; 1.0086x over previous
//
#include <hip/hip_runtime.h>

// ---------------- types / helpers ----------------
typedef __attribute__((ext_vector_type(8))) __bf16 bf16x8;
typedef __attribute__((ext_vector_type(4))) __bf16 bf16x4;
typedef __attribute__((ext_vector_type(4))) float  f32x4;

__device__ __forceinline__ void gld_lds16(const void* g, void* l) {
  __builtin_amdgcn_global_load_lds(
      (const __attribute__((address_space(1))) unsigned int*)g,
      (__attribute__((address_space(3))) unsigned int*)l, 16, 0, 0);
}

// Problem constants: B=2 S=2048 D=768 NQK=12 DQK=64 NOV=768 DOV=1 R=64 VKV=4
// SKV = 2052 (real+virtual keys), SKP = 2112 (padded to 33*64)
// Softmax runs in BASE-2 domain with m == 0 (scores |S|<~1 << f32 exp2 range;
// softmax is shift-invariant and the merge normalizes by L -> exact).
#define QSCALE 0.18033688011112042f

// ---------------- prep: resid + WV bf16 conversions ----------------
__global__ __launch_bounds__(256) void prep_kernel(
    const float* __restrict__ resid, const float* __restrict__ WV,
    __bf16* __restrict__ Rb, __bf16* __restrict__ Wt1)
{
  int t = blockIdx.x * 256 + threadIdx.x;
  if (t < 786432) {               // resid: 4 floats per thread
    f32x4 v = *(const f32x4*)(resid + (size_t)t * 4);
    bf16x4 o;
#pragma unroll
    for (int j = 0; j < 4; ++j) o[j] = (__bf16)v[j];
    *(bf16x4*)(Rb + (size_t)t * 4) = o;
    return;
  }
  t -= 786432;
  if (t < 73728) {                // WV -> Wt1 rows [1536,2304): straight copy, vec8
    const float* vp = WV + (size_t)t * 8;
    f32x4 v0 = *(const f32x4*)vp, v1 = *(const f32x4*)(vp + 4);
    bf16x8 o;
#pragma unroll
    for (int j = 0; j < 8; ++j) o[j] = (__bf16)((j < 4) ? v0[j & 3] : v1[j & 3]);
    *(bf16x8*)(Wt1 + (size_t)1536 * 768 + (size_t)t * 8) = o;
  }
}

// ---------------- LDS-tiled weight transposes ----------------
// grid 432: [0,144) WQ -> Wt1 rows [0,768); [144,288) WK -> rows [768,1536);
// [288,432) WO^T -> Wt2. 64x64 f32 tile via LDS, both sides coalesced.
__global__ __launch_bounds__(256) void wtrans_kernel(
    const float* __restrict__ WQ, const float* __restrict__ WK,
    const float* __restrict__ WO,
    __bf16* __restrict__ Wt1, __bf16* __restrict__ Wt2)
{
  __shared__ float tile[64][65];
  int g = blockIdx.x, tid = threadIdx.x;
  const float* src; __bf16* dst;
  int sld, dld, r0, c0, drow0, dcol0;
  if (g < 288) {                 // WQ / WK: per head [768 k][64 d] -> rows h*64+d, col k
    const float* W = (g < 144) ? WQ : WK;
    int gg = g % 144;
    int h = gg / 12, kt = gg - h * 12;
    src = W + (size_t)h * 49152; sld = 64; r0 = kt * 64; c0 = 0;
    dst = Wt1; dld = 768;
    drow0 = ((g < 144) ? 0 : 768) + h * 64; dcol0 = kt * 64;
  } else {                       // WO [768 nov][768 m] -> Wt2[m][nov]
    int gg = g - 288;
    int rt = gg / 12, ct = gg - rt * 12;
    src = WO; sld = 768; r0 = rt * 64; c0 = ct * 64;
    dst = Wt2; dld = 768; drow0 = ct * 64; dcol0 = rt * 64;
  }
#pragma unroll
  for (int c = 0; c < 4; ++c) {  // load 64 rows x 64 cols f32 (vec4)
    int li = c * 256 + tid;
    int r = li >> 4, cc = (li & 15) * 4;
    f32x4 v = *(const f32x4*)(src + (size_t)(r0 + r) * sld + c0 + cc);
#pragma unroll
    for (int j = 0; j < 4; ++j) tile[r][cc + j] = v[j];
  }
  __syncthreads();
#pragma unroll
  for (int c = 0; c < 2; ++c) {  // store transposed, vec8 bf16
    int li = c * 256 + tid;
    int cc = li >> 3, rr = (li & 7) * 8;
    bf16x8 o;
#pragma unroll
    for (int j = 0; j < 8; ++j) o[j] = (__bf16)tile[rr + j][cc];
    *(bf16x8*)(dst + (size_t)(drow0 + cc) * dld + dcol0 + rr) = o;
  }
}

// ---------------- bf16 GEMM: C[M][N] = A[M][K] * Bt[N][K]^T ----------------
// 128xBN tile, BK=64, 4 waves, double-buffered LDS (2-phase prefetch),
// global_load_lds(16B), XOR-swizzled LDS ((row&7)<<4) via pre-swizzled source.
template<int OUTF, int BN>  // OUTF 0: bf16 out, 1: f32 out; BN in {128, 64}
__global__ __launch_bounds__(256) void gemm_bt(
    const __bf16* __restrict__ A, const __bf16* __restrict__ Bt,
    void* __restrict__ C, int M, int N, int K, int ldc)
{
  constexpr int LDSB = BN * 128;
  constexpr int BUF  = 16384 + LDSB;
  constexpr int BSTG = BN / 32;
  constexpr int IM   = (BN == 128) ? 4 : 2;
  __shared__ __align__(16) char smem[2 * BUF];
  const int tid = threadIdx.x;
  const int l = tid & 63, wv = tid >> 6;
  const int l15 = l & 15, lg = l >> 4;
  const int wmb = (BN == 128) ? (wv >> 1) * 64 : wv * 32;
  const int wnb = (BN == 128) ? (wv & 1) * 64 : 0;
  const int m0 = blockIdx.y * 128, n0 = blockIdx.x * BN;
  const int sw = (l15 & 7) << 4;

  auto stage = [&](int buf, int k0) {
    char* a_l = smem + buf * BUF;
    char* b_l = a_l + 16384;
#pragma unroll
    for (int c = 0; c < 4; ++c) {
      int i2 = c * 256 + tid;
      int row = i2 >> 3, slt = i2 & 7;
      gld_lds16(A + (size_t)(m0 + row) * K + k0 + ((slt ^ (row & 7)) * 8), a_l + i2 * 16);
    }
#pragma unroll
    for (int c = 0; c < BSTG; ++c) {
      int i2 = c * 256 + tid;
      int row = i2 >> 3, slt = i2 & 7;
      gld_lds16(Bt + (size_t)(n0 + row) * K + k0 + ((slt ^ (row & 7)) * 8), b_l + i2 * 16);
    }
  };

  f32x4 acc[IM][4] = {};
  stage(0, 0);
  __syncthreads();
  int cur = 0;
  for (int k0 = 0; k0 < K; k0 += 64) {
    if (k0 + 64 < K) stage(cur ^ 1, k0 + 64);
    char* a_lds = smem + cur * BUF;
    char* b_lds = a_lds + 16384;
#pragma unroll
    for (int kk = 0; kk < 2; ++kk) {
      bf16x8 af[IM], bfr[4];
#pragma unroll
      for (int i = 0; i < IM; ++i) {
        int mr = wmb + i * 16 + l15;
        af[i] = *(const bf16x8*)(a_lds + mr * 128 + ((lg * 16 + kk * 64) ^ sw));
      }
#pragma unroll
      for (int j = 0; j < 4; ++j) {
        int nr = wnb + j * 16 + l15;
        bfr[j] = *(const bf16x8*)(b_lds + nr * 128 + ((lg * 16 + kk * 64) ^ sw));
      }
#pragma unroll
      for (int i = 0; i < IM; ++i)
#pragma unroll
        for (int j = 0; j < 4; ++j)
          acc[i][j] = __builtin_amdgcn_mfma_f32_16x16x32_bf16(af[i], bfr[j], acc[i][j], 0, 0, 0);
    }
    __syncthreads();
    cur ^= 1;
  }
#pragma unroll
  for (int i = 0; i < IM; ++i)
#pragma unroll
    for (int j = 0; j < 4; ++j)
#pragma unroll
      for (int r = 0; r < 4; ++r) {
        int row = m0 + wmb + i * 16 + lg * 4 + r;
        int col = n0 + wnb + j * 16 + l15;
        if (OUTF) ((float*)C)[(size_t)row * ldc + col] = acc[i][j][r];
        else      ((__bf16*)C)[(size_t)row * ldc + col] = (__bf16)acc[i][j][r];
      }
}

// ---------------- rotary + Q/K layout (vectorized) ----------------
// Qb = rope(q+bQ)*QSCALE (base-2 softmax domain); Kb = rope(k+bK) | virtual_k | 0
__global__ __launch_bounds__(256) void qk_rotary(
    const __bf16* __restrict__ qkv, const float* __restrict__ bQ,
    const float* __restrict__ bK, const float* __restrict__ vk,
    const float* __restrict__ rsin, const float* __restrict__ rcos,
    __bf16* __restrict__ Qb, __bf16* __restrict__ Kb)
{
  int t = blockIdx.x * 256 + threadIdx.x;
  if (t < 196608) {
    int d0 = (t & 3) * 8;          // 0,8,16,24  (lower half)
    int x = t >> 2;                // bh*2048 + s
    int bh = x >> 11, s = x & 2047;
    int b = bh / 12, h = bh - b * 12;
    const __bf16* rowp = qkv + ((size_t)(b * 2048 + s)) * 2304 + h * 64;
    bf16x8 ql = *(const bf16x8*)(rowp + d0);
    bf16x8 qu = *(const bf16x8*)(rowp + d0 + 32);
    bf16x8 kl = *(const bf16x8*)(rowp + 768 + d0);
    bf16x8 ku = *(const bf16x8*)(rowp + 768 + d0 + 32);
    const float* bql = bQ + h * 64 + d0;
    const float* bkl = bK + h * 64 + d0;
    const float* snp = rsin + s * 64 + d0;
    const float* csp = rcos + s * 64 + d0;
    f32x4 bq0 = *(const f32x4*)(bql),      bq1 = *(const f32x4*)(bql + 4);
    f32x4 bq2 = *(const f32x4*)(bql + 32), bq3 = *(const f32x4*)(bql + 36);
    f32x4 bk0 = *(const f32x4*)(bkl),      bk1 = *(const f32x4*)(bkl + 4);
    f32x4 bk2 = *(const f32x4*)(bkl + 32), bk3 = *(const f32x4*)(bkl + 36);
    f32x4 sl0 = *(const f32x4*)(snp),      sl1 = *(const f32x4*)(snp + 4);
    f32x4 su0 = *(const f32x4*)(snp + 32), su1 = *(const f32x4*)(snp + 36);
    f32x4 cl0 = *(const f32x4*)(csp),      cl1 = *(const f32x4*)(csp + 4);
    f32x4 cu0 = *(const f32x4*)(csp + 32), cu1 = *(const f32x4*)(csp + 36);
    bf16x8 qlo, quo, klo, kuo;
#pragma unroll
    for (int j = 0; j < 8; ++j) {
      float snl = (j < 4) ? sl0[j & 3] : sl1[j & 3];
      float csl = (j < 4) ? cl0[j & 3] : cl1[j & 3];
      float snu = (j < 4) ? su0[j & 3] : su1[j & 3];
      float csu = (j < 4) ? cu0[j & 3] : cu1[j & 3];
      float q1 = (float)ql[j] + ((j < 4) ? bq0[j & 3] : bq1[j & 3]);
      float q2 = (float)qu[j] + ((j < 4) ? bq2[j & 3] : bq3[j & 3]);
      float k1 = (float)kl[j] + ((j < 4) ? bk0[j & 3] : bk1[j & 3]);
      float k2 = (float)ku[j] + ((j < 4) ? bk2[j & 3] : bk3[j & 3]);
      qlo[j] = (__bf16)((q1 * csl - q2 * snl) * QSCALE);
      quo[j] = (__bf16)((q2 * csu + q1 * snu) * QSCALE);
      klo[j] = (__bf16)(k1 * csl - k2 * snl);
      kuo[j] = (__bf16)(k2 * csu + k1 * snu);
    }
    __bf16* qb = Qb + ((size_t)bh * 2048 + s) * 64;
    __bf16* kb = Kb + ((size_t)bh * 2112 + s) * 64;
    *(bf16x8*)(qb + d0) = qlo;  *(bf16x8*)(qb + d0 + 32) = quo;
    *(bf16x8*)(kb + d0) = klo;  *(bf16x8*)(kb + d0 + 32) = kuo;
    return;
  }
  t -= 196608;                    // K pad region: s in [2048,2112)
  if (t < 12288) {
    int d0 = (t & 7) * 8;
    int x = t >> 3;               // bh*64 + sp
    int bh = x >> 6, sp = x & 63;
    int h = bh % 12;
    bf16x8 o;
    if (sp < 4) {
      const float* vp = vk + ((size_t)sp * 12 + h) * 64 + d0;
      f32x4 v0 = *(const f32x4*)(vp), v1 = *(const f32x4*)(vp + 4);
#pragma unroll
      for (int j = 0; j < 8; ++j) o[j] = (__bf16)((j < 4) ? v0[j & 3] : v1[j & 3]);
    } else {
#pragma unroll
      for (int j = 0; j < 8; ++j) o[j] = (__bf16)0.0f;
    }
    *(bf16x8*)(Kb + ((size_t)bh * 2112 + 2048 + sp) * 64 + d0) = o;
  }
}

// ---------------- V transpose: Vt [24][64 dv][2112 s] (vectorized) ----------------
__global__ __launch_bounds__(256) void v_trans(
    const __bf16* __restrict__ qkv, const float* __restrict__ bV,
    const float* __restrict__ vv, __bf16* __restrict__ Vt)
{
  __shared__ float tile[64][65];
  int st = blockIdx.x, bh = blockIdx.y;
  int b = bh / 12, h = bh - b * 12;
  int tid = threadIdx.x;
#pragma unroll
  for (int c = 0; c < 2; ++c) {
    int chunk = c * 256 + tid;
    int srow = chunk >> 3, d0 = (chunk & 7) * 8;
    int s = st * 64 + srow;
    float vals[8];
    if (s < 2048) {
      bf16x8 v8 = *(const bf16x8*)(qkv + ((size_t)(b * 2048 + s)) * 2304 + 1536 + h * 64 + d0);
      const float* bvp = bV + h * 64 + d0;
      f32x4 b0 = *(const f32x4*)(bvp), b1 = *(const f32x4*)(bvp + 4);
#pragma unroll
      for (int j = 0; j < 8; ++j) vals[j] = (float)v8[j] + ((j < 4) ? b0[j & 3] : b1[j & 3]);
    } else if (s < 2052) {
      const float* vp = vv + (size_t)(s - 2048) * 768 + h * 64 + d0;
      f32x4 v0 = *(const f32x4*)(vp), v1 = *(const f32x4*)(vp + 4);
#pragma unroll
      for (int j = 0; j < 8; ++j) vals[j] = (j < 4) ? v0[j & 3] : v1[j & 3];
    } else {
#pragma unroll
      for (int j = 0; j < 8; ++j) vals[j] = 0.0f;
    }
#pragma unroll
    for (int j = 0; j < 8; ++j) tile[srow][d0 + j] = vals[j];
  }
  __syncthreads();
#pragma unroll
  for (int c = 0; c < 2; ++c) {
    int chunk = c * 256 + tid;
    int drow = chunk >> 3, s0 = (chunk & 7) * 8;
    bf16x8 o8;
#pragma unroll
    for (int j = 0; j < 8; ++j) o8[j] = (__bf16)tile[s0 + j][drow];
    *(bf16x8*)(Vt + ((size_t)bh * 64 + drow) * 2112 + st * 64 + s0) = o8;
  }
}

// ---------------- flash attention, split-K, m==0 softmax ----------------
// Grid 2016 = 24 bh * 84 (qt,split) pairs. Pairs enumerated qt=31..0 (longest
// first), each split covers <=8 key-tiles (512 keys). P = exp2(S) directly
// (no online max -- scores are O(1), exp2 can't overflow; merge normalizes).
// Blocks write UNNORMALIZED partials: O bf16 [64q][64dv], l f32.
__global__ __launch_bounds__(256) void attn_kernel(
    const __bf16* __restrict__ Qb, const __bf16* __restrict__ Kb,
    const __bf16* __restrict__ Vt, __bf16* __restrict__ Opart,
    float* __restrict__ Lsum)
{
  __shared__ __align__(16) char smem[40960];  // 2 x (K 8KB + V 8KB) + P 8KB
  char* p_lds = smem + 32768;
  const int tid = threadIdx.x;
  const int l = tid & 63, w = tid >> 6;
  const int l15 = l & 15, lg = l >> 4;
  const int idx = blockIdx.x;
  const int bh = idx % 24;           // 24 = 3*8 -> 3 heads per XCD
  int pidx = idx / 24;               // 0..83
  int qt = 31, rem = pidx;
  for (;;) { int c = (qt + 9) >> 3; if (rem < c) break; rem -= c; --qt; }
  const int ts = rem * 8;
  const int te = min(ts + 8, qt + 2);
  const int slot = bh * 84 + pidx;
  const int q16 = qt * 64 + w * 16;
  const int sw = (l15 & 7) << 4;
  const int qrow = w * 16 + l15;

  const __bf16* Kbase = Kb + (size_t)bh * 2112 * 64;
  const __bf16* Vbase = Vt + (size_t)bh * 64 * 2112;

  auto stage = [&](int buf, int kt0) {
    char* k_l = smem + buf * 16384;
    char* v_l = k_l + 8192;
#pragma unroll
    for (int c = 0; c < 2; ++c) {
      int i2 = c * 256 + tid;
      int row = i2 >> 3, slt = i2 & 7;
      gld_lds16(Kbase + (kt0 + row) * 64 + ((slt ^ (row & 7)) * 8), k_l + i2 * 16);
    }
#pragma unroll
    for (int c = 0; c < 2; ++c) {
      int i2 = c * 256 + tid;
      int row = i2 >> 3, slt = i2 & 7;
      gld_lds16(Vbase + row * 2112 + kt0 + ((slt ^ (row & 7)) * 8), v_l + i2 * 16);
    }
  };

  stage(0, ts * 64);

  const __bf16* qp = Qb + ((size_t)bh * 2048 + q16 + l15) * 64 + lg * 8;
  const bf16x8 qa0 = *(const bf16x8*)qp;          // Q[q][0..31] B-frag
  const bf16x8 qa1 = *(const bf16x8*)(qp + 32);   // Q[q][32..63]

  f32x4 o[4] = {};
  float lrun = 0.0f;
  __syncthreads();

  int cur = 0;
  for (int kt = ts; kt < te; ++kt) {
    const int kt0 = kt * 64;
    if (kt + 1 < te) stage(cur ^ 1, kt0 + 64);
    char* k_lds = smem + cur * 16384;
    char* v_lds = k_lds + 8192;

    if (kt0 <= q16 + 19) {   // wave has at least one visible key in this tile
      f32x4 sfr[4];
#pragma unroll
      for (int kb = 0; kb < 4; ++kb) {
        int krow = kb * 16 + l15;
        f32x4 a = {};
        bf16x8 ka0 = *(const bf16x8*)(k_lds + krow * 128 + ((lg * 16) ^ sw));
        bf16x8 ka1 = *(const bf16x8*)(k_lds + krow * 128 + ((lg * 16 + 64) ^ sw));
        a = __builtin_amdgcn_mfma_f32_16x16x32_bf16(ka0, qa0, a, 0, 0, 0);
        a = __builtin_amdgcn_mfma_f32_16x16x32_bf16(ka1, qa1, a, 0, 0, 0);
        sfr[kb] = a;
      }
      if (kt >= qt) {  // masked tiles: key visible iff k <= q+4 && k < 2052
        int qlim = q16 + l15 + 4;
#pragma unroll
        for (int kb = 0; kb < 4; ++kb)
#pragma unroll
          for (int r = 0; r < 4; ++r) {
            int kg = kt0 + kb * 16 + lg * 4 + r;
            if (kg > qlim || kg >= 2052) sfr[kb][r] = -1e30f;  // exp2 -> 0
          }
      }
      float rsum = 0.0f;
#pragma unroll
      for (int kb = 0; kb < 4; ++kb) {
        bf16x4 pv;
#pragma unroll
        for (int r = 0; r < 4; ++r) {
          float p = exp2f(sfr[kb][r]);   // m == 0: no max, no subtract
          rsum += p;
          pv[r] = (__bf16)p;
        }
        *(bf16x4*)(p_lds + qrow * 128 + ((kb * 32 + lg * 8) ^ sw)) = pv;
      }
      rsum += __shfl_xor(rsum, 16);
      rsum += __shfl_xor(rsum, 32);
      lrun += rsum;
#pragma unroll
      for (int kblk = 0; kblk < 2; ++kblk) {
        bf16x8 pa = *(const bf16x8*)(p_lds + qrow * 128 + ((kblk * 64 + lg * 16) ^ sw));
#pragma unroll
        for (int dv = 0; dv < 4; ++dv) {
          int vrow = dv * 16 + l15;
          bf16x8 vb = *(const bf16x8*)(v_lds + vrow * 128 + ((kblk * 64 + lg * 16) ^ sw));
          o[dv] = __builtin_amdgcn_mfma_f32_16x16x32_bf16(pa, vb, o[dv], 0, 0, 0);
        }
      }
    }
    __syncthreads();   // drains this iter's prefetch + protects buffers
    cur ^= 1;
  }
  // partial epilogue: unnormalized O (bf16), l (f32)
  if (lg == 0) Lsum[slot * 64 + qrow] = lrun;
  __bf16* op = Opart + (size_t)slot * 4096;
#pragma unroll
  for (int dv = 0; dv < 4; ++dv)
#pragma unroll
    for (int r = 0; r < 4; ++r)
      op[(w * 16 + lg * 4 + r) * 64 + dv * 16 + l15] = (__bf16)o[dv][r];
}

// ---------------- merge split-K partials -> Z ----------------
// grid 768 = 24 bh * 32 qt. m==0 everywhere -> plain sums, then normalize.
__global__ __launch_bounds__(256) void attn_merge(
    const __bf16* __restrict__ Opart, const float* __restrict__ Lsum,
    __bf16* __restrict__ Z)
{
  const int idx = blockIdx.x;
  const int bh = idx % 24, qt = idx / 24;
  const int b = bh / 12, n = bh - b * 12;
  int pbase = 0;
  for (int q2 = 31; q2 > qt; --q2) pbase += (q2 + 9) >> 3;
  const int ns = (qt + 9) >> 3;
  const int t = threadIdx.x;
  const int q = t >> 2, c0 = (t & 3) * 16;

  float L = 0.0f;
  float acc[16] = {};
  for (int s = 0; s < ns; ++s) {
    int slot = bh * 84 + pbase + s;
    L += Lsum[slot * 64 + q];
    const __bf16* op = Opart + (size_t)slot * 4096 + q * 64 + c0;
    bf16x8 o0 = *(const bf16x8*)op, o1 = *(const bf16x8*)(op + 8);
#pragma unroll
    for (int j = 0; j < 8; ++j) {
      acc[j]     += (float)o0[j];
      acc[8 + j] += (float)o1[j];
    }
  }
  float inv = 1.0f / L;
  bf16x8 z0, z1;
#pragma unroll
  for (int j = 0; j < 8; ++j) {
    z0[j] = (__bf16)(acc[j] * inv);
    z1[j] = (__bf16)(acc[8 + j] * inv);
  }
  __bf16* zp = Z + ((size_t)(b * 2048 + qt * 64 + q)) * 768 + n * 64 + c0;
  *(bf16x8*)zp = z0;
  *(bf16x8*)(zp + 8) = z1;
}

// ---------------- launch ----------------
extern "C" void kernel_launch(void* const* d_in, const int* in_sizes, int n_in,
                              void* d_out, int out_size, void* d_ws, size_t ws_size,
                              hipStream_t stream)
{
  const float* resid = (const float*)d_in[0];
  const float* WQ   = (const float*)d_in[1];
  const float* WK   = (const float*)d_in[2];
  const float* WV   = (const float*)d_in[3];
  const float* WO   = (const float*)d_in[4];
  const float* bQ   = (const float*)d_in[5];
  const float* bK   = (const float*)d_in[6];
  const float* bV   = (const float*)d_in[7];
  const float* vk   = (const float*)d_in[8];
  const float* vv   = (const float*)d_in[9];
  const float* rsin = (const float*)d_in[10];
  const float* rcos = (const float*)d_in[11];

  char* ws = (char*)d_ws;
  __bf16* Rb  = (__bf16*)(ws);               // [4096][768]
  __bf16* Wt1 = (__bf16*)(ws + 6291456);     // [2304][768]
  __bf16* Wt2 = (__bf16*)(ws + 9830400);     // [768][768]
  __bf16* QKV = (__bf16*)(ws + 11010048);    // [4096][2304]  (dead after v_trans)
  __bf16* Qb  = (__bf16*)(ws + 29884416);    // [24][2048][64]
  __bf16* Kb  = (__bf16*)(ws + 36175872);    // [24][2112][64]
  __bf16* Vt  = (__bf16*)(ws + 42663936);    // [24][64][2112]
  __bf16* Zb  = (__bf16*)(ws + 49152000);    // [4096][768]
  // split-K partials OVERLAY the dead QKV region (16.5MB + 0.5MB < 18.9MB)
  __bf16* Opart = (__bf16*)(ws + 11010048);          // 2016 x [64][64] bf16
  float*  Lp    = (float*)(ws + 11010048 + 16515072); // 2016 x 64 f32

  prep_kernel<<<3360, 256, 0, stream>>>(resid, WV, Rb, Wt1);
  wtrans_kernel<<<432, 256, 0, stream>>>(WQ, WK, WO, Wt1, Wt2);
  gemm_bt<0, 128><<<dim3(18, 32), 256, 0, stream>>>(Rb, Wt1, (void*)QKV, 4096, 2304, 768, 2304);
  qk_rotary<<<816, 256, 0, stream>>>(QKV, bQ, bK, vk, rsin, rcos, Qb, Kb);
  v_trans<<<dim3(33, 24), 256, 0, stream>>>(QKV, bV, vv, Vt);
  attn_kernel<<<2016, 256, 0, stream>>>(Qb, Kb, Vt, Opart, Lp);
  attn_merge<<<768, 256, 0, stream>>>(Opart, Lp, Zb);
  gemm_bt<1, 64><<<dim3(12, 32), 256, 0, stream>>>(Zb, Wt2, d_out, 4096, 768, 768, 768);
}

// Round 9
// 179.742 us; speedup vs baseline: 1.1848x; 1.0228x over previous
//
#include <hip/hip_runtime.h>

// ---------------- types / helpers ----------------
typedef __attribute__((ext_vector_type(8))) __bf16 bf16x8;
typedef __attribute__((ext_vector_type(4))) __bf16 bf16x4;
typedef __attribute__((ext_vector_type(4))) float  f32x4;

__device__ __forceinline__ void gld_lds16(const void* g, void* l) {
  __builtin_amdgcn_global_load_lds(
      (const __attribute__((address_space(1))) unsigned int*)g,
      (__attribute__((address_space(3))) unsigned int*)l, 16, 0, 0);
}

// counted vmem wait (T4): keep newest N loads in flight across the barrier
template<int N>
__device__ __forceinline__ void wait_vmcnt() {
  if constexpr (N == 0)      asm volatile("s_waitcnt vmcnt(0)" ::: "memory");
  else if constexpr (N == 4) asm volatile("s_waitcnt vmcnt(4)" ::: "memory");
  else if constexpr (N == 6) asm volatile("s_waitcnt vmcnt(6)" ::: "memory");
  else if constexpr (N == 8) asm volatile("s_waitcnt vmcnt(8)" ::: "memory");
}

// Problem constants: B=2 S=2048 D=768 NQK=12 DQK=64 NOV=768 DOV=1 R=64 VKV=4
// SKV = 2052 (real+virtual keys), SKP = 2112 (padded to 33*64)
// Softmax runs in BASE-2 domain with m == 0 (scores |S|<~1 << f32 exp2 range;
// softmax is shift-invariant and the merge normalizes by L -> exact).
#define QSCALE 0.18033688011112042f

// ---------------- prep: resid + WV bf16 conversions ----------------
__global__ __launch_bounds__(256) void prep_kernel(
    const float* __restrict__ resid, const float* __restrict__ WV,
    __bf16* __restrict__ Rb, __bf16* __restrict__ Wt1)
{
  int t = blockIdx.x * 256 + threadIdx.x;
  if (t < 786432) {               // resid: 4 floats per thread
    f32x4 v = *(const f32x4*)(resid + (size_t)t * 4);
    bf16x4 o;
#pragma unroll
    for (int j = 0; j < 4; ++j) o[j] = (__bf16)v[j];
    *(bf16x4*)(Rb + (size_t)t * 4) = o;
    return;
  }
  t -= 786432;
  if (t < 73728) {                // WV -> Wt1 rows [1536,2304): straight copy, vec8
    const float* vp = WV + (size_t)t * 8;
    f32x4 v0 = *(const f32x4*)vp, v1 = *(const f32x4*)(vp + 4);
    bf16x8 o;
#pragma unroll
    for (int j = 0; j < 8; ++j) o[j] = (__bf16)((j < 4) ? v0[j & 3] : v1[j & 3]);
    *(bf16x8*)(Wt1 + (size_t)1536 * 768 + (size_t)t * 8) = o;
  }
}

// ---------------- LDS-tiled weight transposes ----------------
// grid 432: [0,144) WQ -> Wt1 rows [0,768); [144,288) WK -> rows [768,1536);
// [288,432) WO^T -> Wt2. 64x64 f32 tile via LDS, both sides coalesced.
__global__ __launch_bounds__(256) void wtrans_kernel(
    const float* __restrict__ WQ, const float* __restrict__ WK,
    const float* __restrict__ WO,
    __bf16* __restrict__ Wt1, __bf16* __restrict__ Wt2)
{
  __shared__ float tile[64][65];
  int g = blockIdx.x, tid = threadIdx.x;
  const float* src; __bf16* dst;
  int sld, dld, r0, c0, drow0, dcol0;
  if (g < 288) {                 // WQ / WK: per head [768 k][64 d] -> rows h*64+d, col k
    const float* W = (g < 144) ? WQ : WK;
    int gg = g % 144;
    int h = gg / 12, kt = gg - h * 12;
    src = W + (size_t)h * 49152; sld = 64; r0 = kt * 64; c0 = 0;
    dst = Wt1; dld = 768;
    drow0 = ((g < 144) ? 0 : 768) + h * 64; dcol0 = kt * 64;
  } else {                       // WO [768 nov][768 m] -> Wt2[m][nov]
    int gg = g - 288;
    int rt = gg / 12, ct = gg - rt * 12;
    src = WO; sld = 768; r0 = rt * 64; c0 = ct * 64;
    dst = Wt2; dld = 768; drow0 = ct * 64; dcol0 = rt * 64;
  }
#pragma unroll
  for (int c = 0; c < 4; ++c) {  // load 64 rows x 64 cols f32 (vec4)
    int li = c * 256 + tid;
    int r = li >> 4, cc = (li & 15) * 4;
    f32x4 v = *(const f32x4*)(src + (size_t)(r0 + r) * sld + c0 + cc);
#pragma unroll
    for (int j = 0; j < 4; ++j) tile[r][cc + j] = v[j];
  }
  __syncthreads();
#pragma unroll
  for (int c = 0; c < 2; ++c) {  // store transposed, vec8 bf16
    int li = c * 256 + tid;
    int cc = li >> 3, rr = (li & 7) * 8;
    bf16x8 o;
#pragma unroll
    for (int j = 0; j < 8; ++j) o[j] = (__bf16)tile[rr + j][cc];
    *(bf16x8*)(dst + (size_t)(drow0 + cc) * dld + dcol0 + rr) = o;
  }
}

// ---------------- bf16 GEMM: C[M][N] = A[M][K] * Bt[N][K]^T ----------------
// 128xBN tile, BK=64, 4 waves, double-buffered LDS with COUNTED vmcnt (T4):
// prefetch stays in flight across raw s_barriers (no vmcnt(0) drain per tile).
template<int OUTF, int BN>  // OUTF 0: bf16 out, 1: f32 out; BN in {128, 64}
__global__ __launch_bounds__(256) void gemm_bt(
    const __bf16* __restrict__ A, const __bf16* __restrict__ Bt,
    void* __restrict__ C, int M, int N, int K, int ldc)
{
  constexpr int LDSB = BN * 128;
  constexpr int BUF  = 16384 + LDSB;
  constexpr int BSTG = BN / 32;
  constexpr int NLD  = 4 + BSTG;     // gld_lds per thread per stage
  constexpr int IM   = (BN == 128) ? 4 : 2;
  __shared__ __align__(16) char smem[2 * BUF];
  const int tid = threadIdx.x;
  const int l = tid & 63, wv = tid >> 6;
  const int l15 = l & 15, lg = l >> 4;
  const int wmb = (BN == 128) ? (wv >> 1) * 64 : wv * 32;
  const int wnb = (BN == 128) ? (wv & 1) * 64 : 0;
  const int m0 = blockIdx.y * 128, n0 = blockIdx.x * BN;
  const int sw = (l15 & 7) << 4;

  auto stage = [&](int buf, int k0) {
    char* a_l = smem + buf * BUF;
    char* b_l = a_l + 16384;
#pragma unroll
    for (int c = 0; c < 4; ++c) {
      int i2 = c * 256 + tid;
      int row = i2 >> 3, slt = i2 & 7;
      gld_lds16(A + (size_t)(m0 + row) * K + k0 + ((slt ^ (row & 7)) * 8), a_l + i2 * 16);
    }
#pragma unroll
    for (int c = 0; c < BSTG; ++c) {
      int i2 = c * 256 + tid;
      int row = i2 >> 3, slt = i2 & 7;
      gld_lds16(Bt + (size_t)(n0 + row) * K + k0 + ((slt ^ (row & 7)) * 8), b_l + i2 * 16);
    }
  };

  f32x4 acc[IM][4] = {};
  stage(0, 0);
  int cur = 0;
  for (int k0 = 0; k0 < K; k0 += 64) {
    const bool has_next = (k0 + 64 < K);
    if (has_next) stage(cur ^ 1, k0 + 64);     // newest NLD loads in flight
    if (has_next) wait_vmcnt<NLD>(); else wait_vmcnt<0>();  // oldest NLD (buf cur) done
    __builtin_amdgcn_s_barrier();              // raw: no drain
    __builtin_amdgcn_sched_barrier(0);         // pin ds_reads below barrier
    char* a_lds = smem + cur * BUF;
    char* b_lds = a_lds + 16384;
#pragma unroll
    for (int kk = 0; kk < 2; ++kk) {
      bf16x8 af[IM], bfr[4];
#pragma unroll
      for (int i = 0; i < IM; ++i) {
        int mr = wmb + i * 16 + l15;
        af[i] = *(const bf16x8*)(a_lds + mr * 128 + ((lg * 16 + kk * 64) ^ sw));
      }
#pragma unroll
      for (int j = 0; j < 4; ++j) {
        int nr = wnb + j * 16 + l15;
        bfr[j] = *(const bf16x8*)(b_lds + nr * 128 + ((lg * 16 + kk * 64) ^ sw));
      }
#pragma unroll
      for (int i = 0; i < IM; ++i)
#pragma unroll
        for (int j = 0; j < 4; ++j)
          acc[i][j] = __builtin_amdgcn_mfma_f32_16x16x32_bf16(af[i], bfr[j], acc[i][j], 0, 0, 0);
    }
    __builtin_amdgcn_s_barrier();              // all reads of buf cur done before restage
    cur ^= 1;
  }
#pragma unroll
  for (int i = 0; i < IM; ++i)
#pragma unroll
    for (int j = 0; j < 4; ++j)
#pragma unroll
      for (int r = 0; r < 4; ++r) {
        int row = m0 + wmb + i * 16 + lg * 4 + r;
        int col = n0 + wnb + j * 16 + l15;
        if (OUTF) ((float*)C)[(size_t)row * ldc + col] = acc[i][j][r];
        else      ((__bf16*)C)[(size_t)row * ldc + col] = (__bf16)acc[i][j][r];
      }
}

// ---------------- rotary + Q/K layout (vectorized) ----------------
// Qb = rope(q+bQ)*QSCALE (base-2 softmax domain); Kb = rope(k+bK) | virtual_k | 0
__global__ __launch_bounds__(256) void qk_rotary(
    const __bf16* __restrict__ qkv, const float* __restrict__ bQ,
    const float* __restrict__ bK, const float* __restrict__ vk,
    const float* __restrict__ rsin, const float* __restrict__ rcos,
    __bf16* __restrict__ Qb, __bf16* __restrict__ Kb)
{
  int t = blockIdx.x * 256 + threadIdx.x;
  if (t < 196608) {
    int d0 = (t & 3) * 8;          // 0,8,16,24  (lower half)
    int x = t >> 2;                // bh*2048 + s
    int bh = x >> 11, s = x & 2047;
    int b = bh / 12, h = bh - b * 12;
    const __bf16* rowp = qkv + ((size_t)(b * 2048 + s)) * 2304 + h * 64;
    bf16x8 ql = *(const bf16x8*)(rowp + d0);
    bf16x8 qu = *(const bf16x8*)(rowp + d0 + 32);
    bf16x8 kl = *(const bf16x8*)(rowp + 768 + d0);
    bf16x8 ku = *(const bf16x8*)(rowp + 768 + d0 + 32);
    const float* bql = bQ + h * 64 + d0;
    const float* bkl = bK + h * 64 + d0;
    const float* snp = rsin + s * 64 + d0;
    const float* csp = rcos + s * 64 + d0;
    f32x4 bq0 = *(const f32x4*)(bql),      bq1 = *(const f32x4*)(bql + 4);
    f32x4 bq2 = *(const f32x4*)(bql + 32), bq3 = *(const f32x4*)(bql + 36);
    f32x4 bk0 = *(const f32x4*)(bkl),      bk1 = *(const f32x4*)(bkl + 4);
    f32x4 bk2 = *(const f32x4*)(bkl + 32), bk3 = *(const f32x4*)(bkl + 36);
    f32x4 sl0 = *(const f32x4*)(snp),      sl1 = *(const f32x4*)(snp + 4);
    f32x4 su0 = *(const f32x4*)(snp + 32), su1 = *(const f32x4*)(snp + 36);
    f32x4 cl0 = *(const f32x4*)(csp),      cl1 = *(const f32x4*)(csp + 4);
    f32x4 cu0 = *(const f32x4*)(csp + 32), cu1 = *(const f32x4*)(csp + 36);
    bf16x8 qlo, quo, klo, kuo;
#pragma unroll
    for (int j = 0; j < 8; ++j) {
      float snl = (j < 4) ? sl0[j & 3] : sl1[j & 3];
      float csl = (j < 4) ? cl0[j & 3] : cl1[j & 3];
      float snu = (j < 4) ? su0[j & 3] : su1[j & 3];
      float csu = (j < 4) ? cu0[j & 3] : cu1[j & 3];
      float q1 = (float)ql[j] + ((j < 4) ? bq0[j & 3] : bq1[j & 3]);
      float q2 = (float)qu[j] + ((j < 4) ? bq2[j & 3] : bq3[j & 3]);
      float k1 = (float)kl[j] + ((j < 4) ? bk0[j & 3] : bk1[j & 3]);
      float k2 = (float)ku[j] + ((j < 4) ? bk2[j & 3] : bk3[j & 3]);
      qlo[j] = (__bf16)((q1 * csl - q2 * snl) * QSCALE);
      quo[j] = (__bf16)((q2 * csu + q1 * snu) * QSCALE);
      klo[j] = (__bf16)(k1 * csl - k2 * snl);
      kuo[j] = (__bf16)(k2 * csu + k1 * snu);
    }
    __bf16* qb = Qb + ((size_t)bh * 2048 + s) * 64;
    __bf16* kb = Kb + ((size_t)bh * 2112 + s) * 64;
    *(bf16x8*)(qb + d0) = qlo;  *(bf16x8*)(qb + d0 + 32) = quo;
    *(bf16x8*)(kb + d0) = klo;  *(bf16x8*)(kb + d0 + 32) = kuo;
    return;
  }
  t -= 196608;                    // K pad region: s in [2048,2112)
  if (t < 12288) {
    int d0 = (t & 7) * 8;
    int x = t >> 3;               // bh*64 + sp
    int bh = x >> 6, sp = x & 63;
    int h = bh % 12;
    bf16x8 o;
    if (sp < 4) {
      const float* vp = vk + ((size_t)sp * 12 + h) * 64 + d0;
      f32x4 v0 = *(const f32x4*)(vp), v1 = *(const f32x4*)(vp + 4);
#pragma unroll
      for (int j = 0; j < 8; ++j) o[j] = (__bf16)((j < 4) ? v0[j & 3] : v1[j & 3]);
    } else {
#pragma unroll
      for (int j = 0; j < 8; ++j) o[j] = (__bf16)0.0f;
    }
    *(bf16x8*)(Kb + ((size_t)bh * 2112 + 2048 + sp) * 64 + d0) = o;
  }
}

// ---------------- V transpose: Vt [24][64 dv][2112 s] (vectorized) ----------------
__global__ __launch_bounds__(256) void v_trans(
    const __bf16* __restrict__ qkv, const float* __restrict__ bV,
    const float* __restrict__ vv, __bf16* __restrict__ Vt)
{
  __shared__ float tile[64][65];
  int st = blockIdx.x, bh = blockIdx.y;
  int b = bh / 12, h = bh - b * 12;
  int tid = threadIdx.x;
#pragma unroll
  for (int c = 0; c < 2; ++c) {
    int chunk = c * 256 + tid;
    int srow = chunk >> 3, d0 = (chunk & 7) * 8;
    int s = st * 64 + srow;
    float vals[8];
    if (s < 2048) {
      bf16x8 v8 = *(const bf16x8*)(qkv + ((size_t)(b * 2048 + s)) * 2304 + 1536 + h * 64 + d0);
      const float* bvp = bV + h * 64 + d0;
      f32x4 b0 = *(const f32x4*)(bvp), b1 = *(const f32x4*)(bvp + 4);
#pragma unroll
      for (int j = 0; j < 8; ++j) vals[j] = (float)v8[j] + ((j < 4) ? b0[j & 3] : b1[j & 3]);
    } else if (s < 2052) {
      const float* vp = vv + (size_t)(s - 2048) * 768 + h * 64 + d0;
      f32x4 v0 = *(const f32x4*)(vp), v1 = *(const f32x4*)(vp + 4);
#pragma unroll
      for (int j = 0; j < 8; ++j) vals[j] = (j < 4) ? v0[j & 3] : v1[j & 3];
    } else {
#pragma unroll
      for (int j = 0; j < 8; ++j) vals[j] = 0.0f;
    }
#pragma unroll
    for (int j = 0; j < 8; ++j) tile[srow][d0 + j] = vals[j];
  }
  __syncthreads();
#pragma unroll
  for (int c = 0; c < 2; ++c) {
    int chunk = c * 256 + tid;
    int drow = chunk >> 3, s0 = (chunk & 7) * 8;
    bf16x8 o8;
#pragma unroll
    for (int j = 0; j < 8; ++j) o8[j] = (__bf16)tile[s0 + j][drow];
    *(bf16x8*)(Vt + ((size_t)bh * 64 + drow) * 2112 + st * 64 + s0) = o8;
  }
}

// ---------------- flash attention, split-K, m==0, counted-vmcnt pipeline ----
// Grid 2016 = 24 bh * 84 (qt,split) pairs. Each split covers <=8 key-tiles.
// P = exp2(S) directly (no online max). Partials: O bf16 [64q][64dv], l f32.
// T4: raw barriers + vmcnt(4) keep next tile's 4 gld_lds in flight.
__global__ __launch_bounds__(256) void attn_kernel(
    const __bf16* __restrict__ Qb, const __bf16* __restrict__ Kb,
    const __bf16* __restrict__ Vt, __bf16* __restrict__ Opart,
    float* __restrict__ Lsum)
{
  __shared__ __align__(16) char smem[40960];  // 2 x (K 8KB + V 8KB) + P 8KB
  char* p_lds = smem + 32768;
  const int tid = threadIdx.x;
  const int l = tid & 63, w = tid >> 6;
  const int l15 = l & 15, lg = l >> 4;
  const int idx = blockIdx.x;
  const int bh = idx % 24;           // 24 = 3*8 -> 3 heads per XCD
  int pidx = idx / 24;               // 0..83
  int qt = 31, rem = pidx;
  for (;;) { int c = (qt + 9) >> 3; if (rem < c) break; rem -= c; --qt; }
  const int ts = rem * 8;
  const int te = min(ts + 8, qt + 2);
  const int slot = bh * 84 + pidx;
  const int q16 = qt * 64 + w * 16;
  const int sw = (l15 & 7) << 4;
  const int qrow = w * 16 + l15;

  const __bf16* Kbase = Kb + (size_t)bh * 2112 * 64;
  const __bf16* Vbase = Vt + (size_t)bh * 64 * 2112;

  auto stage = [&](int buf, int kt0) {
    char* k_l = smem + buf * 16384;
    char* v_l = k_l + 8192;
#pragma unroll
    for (int c = 0; c < 2; ++c) {
      int i2 = c * 256 + tid;
      int row = i2 >> 3, slt = i2 & 7;
      gld_lds16(Kbase + (kt0 + row) * 64 + ((slt ^ (row & 7)) * 8), k_l + i2 * 16);
    }
#pragma unroll
    for (int c = 0; c < 2; ++c) {
      int i2 = c * 256 + tid;
      int row = i2 >> 3, slt = i2 & 7;
      gld_lds16(Vbase + row * 2112 + kt0 + ((slt ^ (row & 7)) * 8), v_l + i2 * 16);
    }
  };

  stage(0, ts * 64);

  const __bf16* qp = Qb + ((size_t)bh * 2048 + q16 + l15) * 64 + lg * 8;
  const bf16x8 qa0 = *(const bf16x8*)qp;          // Q[q][0..31] B-frag
  const bf16x8 qa1 = *(const bf16x8*)(qp + 32);   // Q[q][32..63]

  f32x4 o[4] = {};
  float lrun = 0.0f;

  int cur = 0;
  for (int kt = ts; kt < te; ++kt) {
    const int kt0 = kt * 64;
    const bool has_next = (kt + 1 < te);
    if (has_next) stage(cur ^ 1, kt0 + 64);    // newest 4 loads in flight
    if (has_next) wait_vmcnt<4>(); else wait_vmcnt<0>();  // oldest 4 (buf cur) done
    __builtin_amdgcn_s_barrier();              // raw: no drain
    __builtin_amdgcn_sched_barrier(0);         // pin ds_reads below barrier
    char* k_lds = smem + cur * 16384;
    char* v_lds = k_lds + 8192;

    if (kt0 <= q16 + 19) {   // wave has at least one visible key in this tile
      f32x4 sfr[4];
#pragma unroll
      for (int kb = 0; kb < 4; ++kb) {
        int krow = kb * 16 + l15;
        f32x4 a = {};
        bf16x8 ka0 = *(const bf16x8*)(k_lds + krow * 128 + ((lg * 16) ^ sw));
        bf16x8 ka1 = *(const bf16x8*)(k_lds + krow * 128 + ((lg * 16 + 64) ^ sw));
        a = __builtin_amdgcn_mfma_f32_16x16x32_bf16(ka0, qa0, a, 0, 0, 0);
        a = __builtin_amdgcn_mfma_f32_16x16x32_bf16(ka1, qa1, a, 0, 0, 0);
        sfr[kb] = a;
      }
      if (kt >= qt) {  // masked tiles: key visible iff k <= q+4 && k < 2052
        int qlim = q16 + l15 + 4;
#pragma unroll
        for (int kb = 0; kb < 4; ++kb)
#pragma unroll
          for (int r = 0; r < 4; ++r) {
            int kg = kt0 + kb * 16 + lg * 4 + r;
            if (kg > qlim || kg >= 2052) sfr[kb][r] = -1e30f;  // exp2 -> 0
          }
      }
      float rsum = 0.0f;
#pragma unroll
      for (int kb = 0; kb < 4; ++kb) {
        bf16x4 pv;
#pragma unroll
        for (int r = 0; r < 4; ++r) {
          float p = exp2f(sfr[kb][r]);   // m == 0: no max, no subtract
          rsum += p;
          pv[r] = (__bf16)p;
        }
        *(bf16x4*)(p_lds + qrow * 128 + ((kb * 32 + lg * 8) ^ sw)) = pv;
      }
      rsum += __shfl_xor(rsum, 16);
      rsum += __shfl_xor(rsum, 32);
      lrun += rsum;
#pragma unroll
      for (int kblk = 0; kblk < 2; ++kblk) {
        bf16x8 pa = *(const bf16x8*)(p_lds + qrow * 128 + ((kblk * 64 + lg * 16) ^ sw));
#pragma unroll
        for (int dv = 0; dv < 4; ++dv) {
          int vrow = dv * 16 + l15;
          bf16x8 vb = *(const bf16x8*)(v_lds + vrow * 128 + ((kblk * 64 + lg * 16) ^ sw));
          o[dv] = __builtin_amdgcn_mfma_f32_16x16x32_bf16(pa, vb, o[dv], 0, 0, 0);
        }
      }
    }
    __builtin_amdgcn_s_barrier();   // all reads of buf cur done before restage
    cur ^= 1;
  }
  // partial epilogue: unnormalized O (bf16), l (f32)
  if (lg == 0) Lsum[slot * 64 + qrow] = lrun;
  __bf16* op = Opart + (size_t)slot * 4096;
#pragma unroll
  for (int dv = 0; dv < 4; ++dv)
#pragma unroll
    for (int r = 0; r < 4; ++r)
      op[(w * 16 + lg * 4 + r) * 64 + dv * 16 + l15] = (__bf16)o[dv][r];
}

// ---------------- merge split-K partials -> Z ----------------
// grid 768 = 24 bh * 32 qt. m==0 everywhere -> plain sums, then normalize.
__global__ __launch_bounds__(256) void attn_merge(
    const __bf16* __restrict__ Opart, const float* __restrict__ Lsum,
    __bf16* __restrict__ Z)
{
  const int idx = blockIdx.x;
  const int bh = idx % 24, qt = idx / 24;
  const int b = bh / 12, n = bh - b * 12;
  int pbase = 0;
  for (int q2 = 31; q2 > qt; --q2) pbase += (q2 + 9) >> 3;
  const int ns = (qt + 9) >> 3;
  const int t = threadIdx.x;
  const int q = t >> 2, c0 = (t & 3) * 16;

  float L = 0.0f;
  float acc[16] = {};
  for (int s = 0; s < ns; ++s) {
    int slot = bh * 84 + pbase + s;
    L += Lsum[slot * 64 + q];
    const __bf16* op = Opart + (size_t)slot * 4096 + q * 64 + c0;
    bf16x8 o0 = *(const bf16x8*)op, o1 = *(const bf16x8*)(op + 8);
#pragma unroll
    for (int j = 0; j < 8; ++j) {
      acc[j]     += (float)o0[j];
      acc[8 + j] += (float)o1[j];
    }
  }
  float inv = 1.0f / L;
  bf16x8 z0, z1;
#pragma unroll
  for (int j = 0; j < 8; ++j) {
    z0[j] = (__bf16)(acc[j] * inv);
    z1[j] = (__bf16)(acc[8 + j] * inv);
  }
  __bf16* zp = Z + ((size_t)(b * 2048 + qt * 64 + q)) * 768 + n * 64 + c0;
  *(bf16x8*)zp = z0;
  *(bf16x8*)(zp + 8) = z1;
}

// ---------------- launch ----------------
extern "C" void kernel_launch(void* const* d_in, const int* in_sizes, int n_in,
                              void* d_out, int out_size, void* d_ws, size_t ws_size,
                              hipStream_t stream)
{
  const float* resid = (const float*)d_in[0];
  const float* WQ   = (const float*)d_in[1];
  const float* WK   = (const float*)d_in[2];
  const float* WV   = (const float*)d_in[3];
  const float* WO   = (const float*)d_in[4];
  const float* bQ   = (const float*)d_in[5];
  const float* bK   = (const float*)d_in[6];
  const float* bV   = (const float*)d_in[7];
  const float* vk   = (const float*)d_in[8];
  const float* vv   = (const float*)d_in[9];
  const float* rsin = (const float*)d_in[10];
  const float* rcos = (const float*)d_in[11];

  char* ws = (char*)d_ws;
  __bf16* Rb  = (__bf16*)(ws);               // [4096][768]
  __bf16* Wt1 = (__bf16*)(ws + 6291456);     // [2304][768]
  __bf16* Wt2 = (__bf16*)(ws + 9830400);     // [768][768]
  __bf16* QKV = (__bf16*)(ws + 11010048);    // [4096][2304]  (dead after v_trans)
  __bf16* Qb  = (__bf16*)(ws + 29884416);    // [24][2048][64]
  __bf16* Kb  = (__bf16*)(ws + 36175872);    // [24][2112][64]
  __bf16* Vt  = (__bf16*)(ws + 42663936);    // [24][64][2112]
  __bf16* Zb  = (__bf16*)(ws + 49152000);    // [4096][768]
  // split-K partials OVERLAY the dead QKV region (16.5MB + 0.5MB < 18.9MB)
  __bf16* Opart = (__bf16*)(ws + 11010048);          // 2016 x [64][64] bf16
  float*  Lp    = (float*)(ws + 11010048 + 16515072); // 2016 x 64 f32

  prep_kernel<<<3360, 256, 0, stream>>>(resid, WV, Rb, Wt1);
  wtrans_kernel<<<432, 256, 0, stream>>>(WQ, WK, WO, Wt1, Wt2);
  gemm_bt<0, 128><<<dim3(18, 32), 256, 0, stream>>>(Rb, Wt1, (void*)QKV, 4096, 2304, 768, 2304);
  qk_rotary<<<816, 256, 0, stream>>>(QKV, bQ, bK, vk, rsin, rcos, Qb, Kb);
  v_trans<<<dim3(33, 24), 256, 0, stream>>>(QKV, bV, vv, Vt);
  attn_kernel<<<2016, 256, 0, stream>>>(Qb, Kb, Vt, Opart, Lp);
  attn_merge<<<768, 256, 0, stream>>>(Opart, Lp, Zb);
  gemm_bt<1, 64><<<dim3(12, 32), 256, 0, stream>>>(Zb, Wt2, d_out, 4096, 768, 768, 768);
}